// Round 1
// baseline (452.769 us; speedup 1.0000x reference)
//
#include <hip/hip_runtime.h>
#include <math.h>

typedef __attribute__((ext_vector_type(8))) short short8;   // 8 bf16
typedef __attribute__((ext_vector_type(4))) short short4v;  // 4 bf16
typedef __attribute__((ext_vector_type(4))) float f32x4;
typedef unsigned int u32;

constexpr int Bsz = 10;
constexpr int Dm  = 256;
constexpr int Hh  = 8;
constexpr int Tt  = 1600;
constexpr int FFd = 2048;
constexpr int Tkv = 802;   // 1 null + 801 compressed
constexpr int JCH = 8;     // j-splits for kv reduction
constexpr size_t Fsz  = (size_t)Bsz * Tt * Dm;    // 4,096,000
constexpr size_t PAD  = 65536;
constexpr size_t KVsz = (size_t)Bsz * Tkv * Dm;   // 2,053,120
constexpr size_t FHsz = (size_t)Bsz * Tt * FFd;   // 32,768,000
constexpr size_t WBsz = 2621440;                  // all weights, bf16

// Static device scratch; referenced ONLY from device code.
__device__ float g_x[Fsz];                        // residual stream fp32
__device__ float g_qk[Fsz];                       // FF2 out (LN2 delta)
__device__ float g_t[Fsz];                        // Wo out (LN1 delta)
__device__ float g_kc[KVsz];                      // compressed K
__device__ float g_vc[KVsz];                      // compressed V
__device__ float g_kvm[(size_t)Bsz * Hh * 32 * 32];
__device__ float g_kvp[(size_t)JCH * Bsz * Hh * 32 * 32];
__device__ float g_pos[Fsz];                      // transposed pos fp32
__device__ unsigned short g_xb[Fsz + PAD];        // bf16 shadow of x
__device__ unsigned short g_qkb[Fsz + PAD];       // bf16 x+pos
__device__ unsigned short g_tb[Fsz + PAD];        // bf16 k/v projections
__device__ unsigned short g_qb[Fsz + PAD];        // bf16 q projection
__device__ unsigned short g_ffh[FHsz + PAD];      // bf16 FF hidden
__device__ unsigned short g_wb[WBsz];             // bf16 weights
__device__ unsigned short g_wo2[(size_t)Bsz * Dm * Dm];  // per-b fused kvm*Wo

__device__ __forceinline__ float* selbuf(int id) {
  switch (id) {
    case 0: return g_x;
    case 1: return g_qk;
    case 2: return g_t;
    case 3: return g_kc;
    case 4: return g_vc;
    default: return g_kvm;
  }
}
__device__ __forceinline__ unsigned short* selbufb(int id) {
  switch (id) {
    case 0: return g_xb;
    case 1: return g_qkb;
    case 2: return g_tb;
    case 3: return g_ffh;
    default: return g_qb;
  }
}

// fp32 -> bf16 (RNE)
__device__ __forceinline__ unsigned short f2b(float x) {
  unsigned int u = __float_as_uint(x);
  u += 0x7FFFu + ((u >> 16) & 1u);
  return (unsigned short)(u >> 16);
}
__device__ __forceinline__ float b2f(unsigned short u) {
  return __uint_as_float(((unsigned int)u) << 16);
}

// ---------------------------------------------------------------------------
__global__ __launch_bounds__(256) void wconv_k(const float* src, int dstoff, int n) {
  int i = blockIdx.x * 256 + threadIdx.x;
  if (i < n) g_wb[dstoff + i] = f2b(src[i]);
}

// ---------------------------------------------------------------------------
// Transpose src [B,D,T] -> g_x [B,T,D] (+ bf16 shadow), or pose -> g_pos.
__global__ __launch_bounds__(256) void trans_in_k(const float* in, int oid) {
  __shared__ float tile[32][33];
  const int tx = threadIdx.x & 31, ty = threadIdx.x >> 5;
  const int t0 = blockIdx.x * 32, d0 = blockIdx.y * 32, b = blockIdx.z;
  #pragma unroll
  for (int i = ty; i < 32; i += 8)
    tile[i][tx] = in[((size_t)(b * Dm + d0 + i)) * Tt + t0 + tx];
  __syncthreads();
  float* out = (oid == 0) ? g_x : g_pos;
  #pragma unroll
  for (int i = ty; i < 32; i += 8) {
    const size_t idx = ((size_t)(b * Tt + t0 + i)) * Dm + d0 + tx;
    float v = tile[tx][i];
    out[idx] = v;
    if (oid == 0) g_xb[idx] = f2b(v);
  }
}

__global__ __launch_bounds__(256) void trans_out_k(float* out) {
  __shared__ float tile[32][33];
  const int tx = threadIdx.x & 31, ty = threadIdx.x >> 5;
  const int t0 = blockIdx.x * 32, d0 = blockIdx.y * 32, b = blockIdx.z;
  #pragma unroll
  for (int i = ty; i < 32; i += 8)
    tile[i][tx] = g_x[((size_t)(b * Tt + t0 + i)) * Dm + d0 + tx];
  __syncthreads();
  #pragma unroll
  for (int i = ty; i < 32; i += 8)
    out[((size_t)(b * Dm + d0 + i)) * Tt + t0 + tx] = tile[tx][i];
}

// g_qkb = bf16(g_x + g_pos)
__global__ __launch_bounds__(256) void addpos_k(int n4) {
  int i = blockIdx.x * 256 + threadIdx.x;
  if (i >= n4) return;
  float4 a = ((const float4*)g_x)[i];
  float4 p = ((const float4*)g_pos)[i];
  short4v v;
  v[0] = (short)f2b(a.x + p.x); v[1] = (short)f2b(a.y + p.y);
  v[2] = (short)f2b(a.z + p.z); v[3] = (short)f2b(a.w + p.w);
  *(short4v*)&g_qkb[(size_t)i * 4] = v;
}

// ---------------------------------------------------------------------------
// MFMA GEMM: C[M,N] = A[M,K](bf16) @ W[N,K](bf16)^T (+bias)(+relu).
// BM=128, BN in {64,128}, BK=64; 4 waves (2x2). 1-D grid + bijective XCD
// swizzle; counted-vmcnt 2-deep pipeline; LDS-staged coalesced epilogue.
// BN=128 gives each wave a 64x64 tile: 8 ds_read_b128 per 16 MFMA (ratio
// 0.5 vs 0.75 at BN=64) and halves A-panel staging redundancy.
// DUAL (N=512 merged KQ): n0<256 -> Cid, n0>=256 -> C2id, stride 256.
// PERB: per-batch weights g_wo2 (13 m-blocks x NB per b), guarded stores.
template<int BN, bool DUAL, bool PERB, bool RELU, bool BIAS, bool CBF16>
__global__ __launch_bounds__(256) void gemm2_k(
    int Aid, int woff, const float* __restrict__ bias, int Cid, int C2id,
    int NB, int M, int N, int K) {
  constexpr int BM = 128, BK = 64;
  constexpr int ACH = BM * 8;           // 1024 short8
  constexpr int BCH = BN * 8;           // 512 or 1024
  constexpr int NW = BN / 32;           // n-frags per wave: 2 or 4
  __shared__ short8 As8[2][ACH];
  __shared__ short8 Bs8[2][BCH];
  const int tid = threadIdx.x;
  const int lane = tid & 63, wid = tid >> 6;
  const int wr = wid >> 1, wc = wid & 1;

  // XCD-aware bijective remap (m204).
  const int nwg = gridDim.x;
  const int bid = blockIdx.x;
  const int q = nwg >> 3, r = nwg & 7;
  const int xcd = bid & 7, seq = bid >> 3;
  const int wgid = (xcd < r ? xcd * (q + 1) : r * (q + 1) + (xcd - r) * q) + seq;

  int m0, n0, mlim;
  const unsigned short* W16;
  if constexpr (PERB) {
    const int per = 13 * NB;
    const int b = wgid / per;
    const int rem = wgid - b * per;
    m0 = b * Tt + (rem / NB) * BM;
    n0 = (rem % NB) * BN;
    mlim = b * Tt + Tt;
    W16 = g_wo2 + (size_t)b * 65536;
  } else {
    m0 = (wgid / NB) * BM;
    n0 = (wgid % NB) * BN;
    mlim = M;
    W16 = g_wb + woff;
  }

  const unsigned short* A16 = selbufb(Aid);
  const bool second = DUAL && (n0 >= 256);
  float* Cf = selbuf(second ? C2id : Cid);
  unsigned short* C16 = selbufb(second ? C2id : Cid);
  const int gn0 = second ? n0 - 256 : n0;
  const int cstride = DUAL ? 256 : N;

  f32x4 acc[4][NW];
  #pragma unroll
  for (int m = 0; m < 4; ++m)
    #pragma unroll
    for (int n = 0; n < NW; ++n) acc[m][n] = (f32x4){0.f, 0.f, 0.f, 0.f};

  const int lkc = lane >> 4, lrc = lane & 15;

  auto stage = [&](int t, int buf) {
    const int k0 = t * BK;
    #pragma unroll
    for (int i = 0; i < ACH / 256; ++i) {
      const int c = tid + i * 256;
      const int row = c >> 3, kc = c & 7;
      const unsigned short* gs = A16 + (size_t)(m0 + row) * K + k0 +
                                 ((kc ^ (row & 7)) << 3);
      __builtin_amdgcn_global_load_lds(
          (const __attribute__((address_space(1))) u32*)gs,
          (__attribute__((address_space(3))) u32*)&As8[buf][c], 16, 0, 0);
    }
    #pragma unroll
    for (int i = 0; i < BCH / 256; ++i) {
      const int c = tid + i * 256;
      const int row = c >> 3, kc = c & 7;
      const unsigned short* gs = W16 + (size_t)(n0 + row) * K + k0 +
                                 ((kc ^ (row & 7)) << 3);
      __builtin_amdgcn_global_load_lds(
          (const __attribute__((address_space(1))) u32*)gs,
          (__attribute__((address_space(3))) u32*)&Bs8[buf][c], 16, 0, 0);
    }
  };

  const int nt = K / BK;
  stage(0, 0);
  if (nt > 1) stage(1, 1);
  for (int t = 0; t < nt; ++t) {
    const int cur = t & 1;
    if (t + 1 < nt) {
      if constexpr (BN == 64)
        asm volatile("s_waitcnt vmcnt(6)" ::: "memory");
      else
        asm volatile("s_waitcnt vmcnt(8)" ::: "memory");
    } else {
      asm volatile("s_waitcnt vmcnt(0)" ::: "memory");
    }
    __builtin_amdgcn_sched_barrier(0);
    __builtin_amdgcn_s_barrier();       // buf[cur] visible to all waves
    #pragma unroll
    for (int kk = 0; kk < 2; ++kk) {
      short8 af[4], bf[NW];
      #pragma unroll
      for (int m = 0; m < 4; ++m) {
        const int r2 = wr * 64 + m * 16 + lrc;
        af[m] = As8[cur][r2 * 8 + ((kk * 4 + lkc) ^ (r2 & 7))];
      }
      #pragma unroll
      for (int n = 0; n < NW; ++n) {
        const int cn = wc * (BN / 2) + n * 16 + lrc;
        bf[n] = Bs8[cur][cn * 8 + ((kk * 4 + lkc) ^ (cn & 7))];
      }
      #pragma unroll
      for (int m = 0; m < 4; ++m)
        #pragma unroll
        for (int n = 0; n < NW; ++n)
          acc[m][n] = __builtin_amdgcn_mfma_f32_16x16x32_bf16(
              af[m], bf[n], acc[m][n], 0, 0, 0);
    }
    __builtin_amdgcn_sched_barrier(0);
    __builtin_amdgcn_s_barrier();       // all waves done reading buf[cur]
    __builtin_amdgcn_sched_barrier(0);
    if (t + 2 < nt) stage(t + 2, cur);  // overwrite buf[cur] for t+2
  }

  // ---- LDS-staged epilogue: deposit acc, then coalesced row stores ----
  constexpr int CSTR = (BN == 64) ? BN + 4 : BN;
  float* ldsC = (float*)&As8[0][0];
  {
    asm volatile("s_waitcnt vmcnt(0)" ::: "memory");
    __builtin_amdgcn_s_barrier();
    const int r0 = lkc * 4;
    #pragma unroll
    for (int m = 0; m < 4; ++m)
      #pragma unroll
      for (int n = 0; n < NW; ++n) {
        const int col = wc * (BN / 2) + n * 16 + lrc;
        #pragma unroll
        for (int j = 0; j < 4; ++j)
          ldsC[(wr * 64 + m * 16 + r0 + j) * CSTR + col] = acc[m][n][j];
      }
    __syncthreads();
  }
  if constexpr (CBF16) {
    constexpr int CH = BM * BN / 8;     // short8 chunks
    #pragma unroll
    for (int i = 0; i < CH / 256; ++i) {
      const int c = tid + i * 256;
      const int rowl = c / (BN / 8), col8 = (c % (BN / 8)) * 8;
      if (PERB && m0 + rowl >= mlim) continue;
      short8 v;
      #pragma unroll
      for (int j = 0; j < 8; ++j) {
        float x = ldsC[rowl * CSTR + col8 + j];
        if (BIAS) x += bias[gn0 + col8 + j];
        if (RELU) x = fmaxf(x, 0.f);
        v[j] = (short)f2b(x);
      }
      *(short8*)(C16 + (size_t)(m0 + rowl) * cstride + gn0 + col8) = v;
    }
  } else {
    constexpr int CH = BM * BN / 4;     // float4 chunks
    #pragma unroll
    for (int i = 0; i < CH / 256; ++i) {
      const int c = tid + i * 256;
      const int rowl = c / (BN / 4), col4 = (c % (BN / 4)) * 4;
      if (PERB && m0 + rowl >= mlim) continue;
      float4 v;
      float* pv = &v.x;
      #pragma unroll
      for (int j = 0; j < 4; ++j) {
        float x = ldsC[rowl * CSTR + col4 + j];
        if (BIAS) x += bias[gn0 + col4 + j];
        if (RELU) x = fmaxf(x, 0.f);
        pv[j] = x;
      }
      *(float4*)(Cf + (size_t)(m0 + rowl) * cstride + gn0 + col4) = v;
    }
  }
}

// ---------------------------------------------------------------------------
// Conv compression (tc = 1..800) + edge rows (j=0 null, j=1 bias) in block 0.
__global__ __launch_bounds__(256) void compress_main_k(
    const float* __restrict__ cw, const float* __restrict__ cb,
    const float* __restrict__ nul, int out_id) {
  __shared__ float rows[32][256];       // 32 KB
  const int tc0 = 1 + blockIdx.x * 16;
  const int b = blockIdx.y;
  const int tid = threadIdx.x;
  const int o = tid;
  const int g = o >> 5;

  const int r0g = 2 * tc0 - 2;
  const unsigned short* src = g_tb + ((size_t)b * Tt + r0g) * Dm;
  #pragma unroll
  for (int i = 0; i < 4; ++i) {
    const int c = tid + i * 256;        // 1024 chunks of 8
    const int row = c >> 5, off = (c & 31) * 8;
    short8 v = *(const short8*)(src + (size_t)row * 256 + off);
    #pragma unroll
    for (int j = 0; j < 8; ++j)
      rows[row][off + j] = b2f((unsigned short)v[j]);
  }

  float we[32], wo[32];
  {
    const float4* wp = (const float4*)(cw + o * 64);
    #pragma unroll
    for (int i = 0; i < 16; ++i) {
      float4 w4 = wp[i];
      we[i * 2 + 0] = w4.x; wo[i * 2 + 0] = w4.y;
      we[i * 2 + 1] = w4.z; wo[i * 2 + 1] = w4.w;
    }
  }
  const float bias = cb[o];
  float* outb = selbuf(out_id) + (size_t)b * Tkv * Dm;
  if (blockIdx.x == 0) {                // edge rows j=0,1
    outb[o] = nul[b * Dm + o];
    outb[Dm + o] = bias;
  }
  __syncthreads();

  float* outp = outb + o;
  #pragma unroll
  for (int t = 0; t < 16; ++t) {
    const int lr = 2 * t;
    const float* p0 = &rows[lr][g * 32];
    const float* p1 = &rows[lr + 1][g * 32];
    float acc = bias;
    #pragma unroll
    for (int i4 = 0; i4 < 8; ++i4) {
      float4 a0 = *(const float4*)(p0 + i4 * 4);
      float4 a1 = *(const float4*)(p1 + i4 * 4);
      acc = fmaf(we[i4 * 4 + 0], a0.x, acc);
      acc = fmaf(we[i4 * 4 + 1], a0.y, acc);
      acc = fmaf(we[i4 * 4 + 2], a0.z, acc);
      acc = fmaf(we[i4 * 4 + 3], a0.w, acc);
      acc = fmaf(wo[i4 * 4 + 0], a1.x, acc);
      acc = fmaf(wo[i4 * 4 + 1], a1.y, acc);
      acc = fmaf(wo[i4 * 4 + 2], a1.z, acc);
      acc = fmaf(wo[i4 * 4 + 3], a1.w, acc);
    }
    outp[(size_t)(1 + tc0 + t) * Dm] = acc;
  }
}

// ---------------------------------------------------------------------------
// KV reduction stage 1/2 (validated).
__global__ __launch_bounds__(256) void kvout1_k() {
  __shared__ float kl[8][32];
  __shared__ float vl[8][32];
  const int bh = blockIdx.x;
  const int js = blockIdx.y;
  const int b = bh >> 3, h = bh & 7;
  const int j0 = js * 101;
  const int jend = (j0 + 101 < Tkv) ? j0 + 101 : Tkv;

  const int tid = threadIdx.x;
  const int lr = tid >> 5;
  const int lc = tid & 31;
  const int e = tid >> 3;
  const int d0 = (tid & 7) * 4;

  float a0 = 0.f, a1 = 0.f, a2 = 0.f, a3 = 0.f;
  const size_t base = (size_t)b * Tkv * Dm + h * 32;

  for (int jc = j0; jc < jend; jc += 8) {
    const int jr = jc + lr;
    if (jr < jend) {
      kl[lr][lc] = g_kc[base + (size_t)jr * Dm + lc];
      vl[lr][lc] = g_vc[base + (size_t)jr * Dm + lc];
    } else {
      kl[lr][lc] = 0.f;
      vl[lr][lc] = 0.f;
    }
    __syncthreads();
    #pragma unroll
    for (int r = 0; r < 8; ++r) {
      const float kf = kl[r][e];
      const float* vr = &vl[r][d0];
      a0 = fmaf(kf, vr[0], a0);
      a1 = fmaf(kf, vr[1], a1);
      a2 = fmaf(kf, vr[2], a2);
      a3 = fmaf(kf, vr[3], a3);
    }
    __syncthreads();
  }
  float* op = g_kvp + ((size_t)js * 80 + bh) * 1024 + e * 32 + d0;
  op[0] = a0; op[1] = a1; op[2] = a2; op[3] = a3;
}

__global__ __launch_bounds__(256) void kvout2_k() {
  const int bh = blockIdx.x;
  const int tid = threadIdx.x;
  const int e = tid >> 3;
  const int d0 = (tid & 7) * 4;
  float a0 = 0.f, a1 = 0.f, a2 = 0.f, a3 = 0.f;
  #pragma unroll
  for (int s = 0; s < JCH; ++s) {
    const float* p = g_kvp + ((size_t)s * 80 + bh) * 1024 + e * 32 + d0;
    a0 += p[0]; a1 += p[1]; a2 += p[2]; a3 += p[3];
  }
  float* op = g_kvm + (size_t)bh * 1024 + e * 32 + d0;
  op[0] = a0 * 0.0625f;
  op[1] = a1 * 0.0625f;
  op[2] = a2 * 0.0625f;
  op[3] = a3 * 0.0625f;
}

// ---------------------------------------------------------------------------
// W'[b,n,h*32+e] = sum_d kvm[b,h,e,d] * Wo[n,h*32+d]   (bf16 out)
__global__ __launch_bounds__(256) void wo2_k(int wooff) {
  const int n = blockIdx.x, b = blockIdx.y;
  const int he = threadIdx.x;
  const int h = he >> 5, e = he & 31;
  const float* kp = g_kvm + ((size_t)(b * Hh + h) * 32 + e) * 32;
  const unsigned short* wp = g_wb + wooff + (size_t)n * Dm + h * 32;
  float acc = 0.f;
  #pragma unroll
  for (int d = 0; d < 32; ++d) acc = fmaf(kp[d], b2f(wp[d]), acc);
  g_wo2[(size_t)b * 65536 + (size_t)n * Dm + he] = f2b(acc);
}

// ---------------------------------------------------------------------------
// x = LN(x + delta)*g + beta (fp32), writes bf16 shadow g_xb.
// If do_pos: also writes g_qkb = bf16(ln_out + pos).
__global__ __launch_bounds__(256) void ln_k(int did, const float* g,
                                            const float* beta, int do_pos) {
  const int lane = threadIdx.x & 63;
  const int wave = threadIdx.x >> 6;
  const size_t row = (size_t)blockIdx.x * 4 + wave;
  float4 xv = ((const float4*)g_x)[row * 64 + lane];
  float4 dv = ((const float4*)selbuf(did))[row * 64 + lane];
  float v[4] = {xv.x + dv.x, xv.y + dv.y, xv.z + dv.z, xv.w + dv.w};
  float sum = v[0] + v[1] + v[2] + v[3];
  float sq = v[0]*v[0] + v[1]*v[1] + v[2]*v[2] + v[3]*v[3];
  #pragma unroll
  for (int off = 32; off; off >>= 1) {
    sum += __shfl_xor(sum, off);
    sq  += __shfl_xor(sq, off);
  }
  const float mean = sum * (1.f / 256.f);
  const float var = sq * (1.f / 256.f) - mean * mean;
  const float rs = rsqrtf(var + 1e-5f);
  float4 gg = ((const float4*)g)[lane];
  float4 bb = ((const float4*)beta)[lane];
  float4 ov;
  ov.x = (v[0] - mean) * rs * gg.x + bb.x;
  ov.y = (v[1] - mean) * rs * gg.y + bb.y;
  ov.z = (v[2] - mean) * rs * gg.z + bb.z;
  ov.w = (v[3] - mean) * rs * gg.w + bb.w;
  ((float4*)g_x)[row * 64 + lane] = ov;
  short4v sv;
  sv[0] = (short)f2b(ov.x); sv[1] = (short)f2b(ov.y);
  sv[2] = (short)f2b(ov.z); sv[3] = (short)f2b(ov.w);
  *(short4v*)&g_xb[(row * 64 + lane) * 4] = sv;
  if (do_pos) {
    float4 pv = ((const float4*)g_pos)[row * 64 + lane];
    short4v qv;
    qv[0] = (short)f2b(ov.x + pv.x); qv[1] = (short)f2b(ov.y + pv.y);
    qv[2] = (short)f2b(ov.z + pv.z); qv[3] = (short)f2b(ov.w + pv.w);
    *(short4v*)&g_qkb[(row * 64 + lane) * 4] = qv;
  }
}

// ---------------------------------------------------------------------------
extern "C" void kernel_launch(void* const* d_in, const int* in_sizes, int n_in,
                              void* d_out, int out_size, void* d_ws, size_t ws_size,
                              hipStream_t stream) {
  const float* src  = (const float*)d_in[0];
  const float* pose = (const float*)d_in[1];
  const float* Wq   = (const float*)d_in[2];
  const float* Wk   = (const float*)d_in[3];
  const float* Wv   = (const float*)d_in[4];
  const float* Wo   = (const float*)d_in[5];
  const float* bo   = (const float*)d_in[6];
  const float* cw   = (const float*)d_in[7];
  const float* cb   = (const float*)d_in[8];
  const float* nk   = (const float*)d_in[9];
  const float* nv   = (const float*)d_in[10];
  const float* ln1g = (const float*)d_in[11];
  const float* ln1b = (const float*)d_in[12];
  const float* ln2g = (const float*)d_in[13];
  const float* ln2b = (const float*)d_in[14];
  const float* W1   = (const float*)d_in[15];
  const float* b1   = (const float*)d_in[16];
  const float* W2   = (const float*)d_in[17];
  const float* b2   = (const float*)d_in[18];

  const int MT = Bsz * Tt;        // 16000
  const int NF = (int)Fsz;        // 4,096,000
  const dim3 tgrid(Tt / 32, Dm / 32, Bsz);

  // g_wb layout: per-layer [Wk|Wq] at l*131072; then Wv, Wo, W1, W2.
  const int OV = 262144, OO = 393216, O1 = 524288, O2 = 1572864;
  for (int l = 0; l < 2; ++l) {
    wconv_k<<<256, 256, 0, stream>>>(Wk + (size_t)l * 65536, l * 131072, 65536);
    wconv_k<<<256, 256, 0, stream>>>(Wq + (size_t)l * 65536, l * 131072 + 65536, 65536);
    wconv_k<<<256, 256, 0, stream>>>(Wv + (size_t)l * 65536, OV + l * 65536, 65536);
    wconv_k<<<256, 256, 0, stream>>>(Wo + (size_t)l * 65536, OO + l * 65536, 65536);
  }
  wconv_k<<<4096, 256, 0, stream>>>(W1, O1, 1048576);
  wconv_k<<<4096, 256, 0, stream>>>(W2, O2, 1048576);

  trans_in_k<<<tgrid, 256, 0, stream>>>(src, 0);    // writes g_x + g_xb
  trans_in_k<<<tgrid, 256, 0, stream>>>(pose, 7);

  const int MB = MT / 128;  // 125 m-blocks
  for (int l = 0; l < 2; ++l) {
    const float* bo_l = bo + (size_t)l * Dm;
    const float* cw_l = cw + (size_t)l * Dm * 64;
    const float* cb_l = cb + (size_t)l * Dm;
    const float* nk_l = nk + (size_t)l * Bsz * Dm;
    const float* nv_l = nv + (size_t)l * Bsz * Dm;
    const float* b1_l = b1 + (size_t)l * FFd;
    const float* b2_l = b2 + (size_t)l * Dm;
    const int wkq = l * 131072;
    const int wv = OV + l * 65536, wo = OO + l * 65536;
    const int w1 = O1 + l * 524288, w2 = O2 + l * 524288;

    // qkb = bf16(x + pos): layer 0 explicit; layer 1 from fused LN2.
    if (l == 0) addpos_k<<<NF / 4 / 256, 256, 0, stream>>>(NF / 4);
    // [k|q] = qkb @ [Wk|Wq]^T : k -> tb, q -> qb (N=512 dual-dest, NB=4)
    gemm2_k<128, true, false, false, false, true><<<4 * MB, 256, 0, stream>>>(
        1, wkq, nullptr, 2, 4, 4, MT, 512, Dm);
    compress_main_k<<<dim3(50, Bsz), 256, 0, stream>>>(cw_l, cb_l, nk_l, 3);
    // v = xb @ Wv^T -> tb ; compress -> vc  (NB=2)
    gemm2_k<128, false, false, false, false, true><<<2 * MB, 256, 0, stream>>>(
        0, wv, nullptr, 2, 0, 2, MT, Dm, Dm);
    compress_main_k<<<dim3(50, Bsz), 256, 0, stream>>>(cw_l, cb_l, nv_l, 4);
    // kvm = (1/16) kc^T vc
    kvout1_k<<<dim3(Bsz * Hh, JCH), 256, 0, stream>>>();
    kvout2_k<<<Bsz * Hh, 256, 0, stream>>>();
    // W' = kvm (×) Wo  (per-b fused attn+Wo weights)
    wo2_k<<<dim3(Dm, Bsz), 256, 0, stream>>>(wo);
    // t = qb @ W'^T + bo (fp32, per-b) ; x = LN(x + t)
    gemm2_k<128, false, true, false, true, false><<<Bsz * 13 * 2, 256, 0, stream>>>(
        4, 0, bo_l, 2, 0, 2, MT, Dm, Dm);
    ln_k<<<MT / 4, 256, 0, stream>>>(2, ln1g + l * Dm, ln1b + l * Dm, 0);

    // FF1: ffh = bf16(relu(xb @ W1^T + b1))  [BN=128, NB=16, grid 2000]
    gemm2_k<128, false, false, true, true, true><<<16 * MB, 256, 0, stream>>>(
        0, w1, b1_l, 3, 0, 16, MT, FFd, Dm);
    // FF2: qk = ffh @ W2^T + b2 (fp32)  [BN=128, NB=2, grid 250]
    gemm2_k<128, false, false, false, true, false><<<2 * MB, 256, 0, stream>>>(
        3, w2, b2_l, 1, 0, 2, MT, Dm, FFd);
    // LN2: layer 0 fused with next layer's pos-add (writes qkb).
    ln_k<<<MT / 4, 256, 0, stream>>>(1, ln2g + l * Dm, ln2b + l * Dm,
                                     l == 0 ? 1 : 0);
  }

  trans_out_k<<<tgrid, 256, 0, stream>>>((float*)d_out);
}

// Round 2
// 409.409 us; speedup vs baseline: 1.1059x; 1.1059x over previous
//
#include <hip/hip_runtime.h>
#include <math.h>

typedef __attribute__((ext_vector_type(8))) short short8;   // 8 bf16
typedef __attribute__((ext_vector_type(4))) short short4v;  // 4 bf16
typedef __attribute__((ext_vector_type(4))) float f32x4;
typedef unsigned int u32;

constexpr int Bsz = 10;
constexpr int Dm  = 256;
constexpr int Hh  = 8;
constexpr int Tt  = 1600;
constexpr int FFd = 2048;
constexpr int Tkv = 802;   // 1 null + 801 compressed
constexpr int JCH = 8;     // j-splits for kv reduction
constexpr size_t Fsz  = (size_t)Bsz * Tt * Dm;    // 4,096,000
constexpr size_t PAD  = 65536;
constexpr size_t KVsz = (size_t)Bsz * Tkv * Dm;   // 2,053,120
constexpr size_t FHsz = (size_t)Bsz * Tt * FFd;   // 32,768,000
constexpr size_t WBsz = 2621440;                  // all weights, bf16

// Static device scratch; referenced ONLY from device code.
__device__ float g_x[Fsz];                        // residual stream fp32
__device__ float g_qk[Fsz];                       // FF2 out (LN2 delta)
__device__ float g_t[Fsz];                        // Wo out (LN1 delta)
__device__ float g_kc[KVsz];                      // compressed K
__device__ float g_vc[KVsz];                      // compressed V
__device__ float g_kvm[(size_t)Bsz * Hh * 32 * 32];
__device__ float g_kvp[(size_t)JCH * Bsz * Hh * 32 * 32];
__device__ float g_pos[Fsz];                      // transposed pos fp32
__device__ unsigned short g_xb[Fsz + PAD];        // bf16 shadow of x
__device__ unsigned short g_qkb[Fsz + PAD];       // bf16 x+pos
__device__ unsigned short g_tb[Fsz + PAD];        // bf16 k/v projections
__device__ unsigned short g_qb[Fsz + PAD];        // bf16 q projection
__device__ unsigned short g_ffh[FHsz + PAD];      // bf16 FF hidden
__device__ unsigned short g_wb[WBsz];             // bf16 weights
__device__ unsigned short g_wo2[(size_t)Bsz * Dm * Dm];  // per-b fused kvm*Wo

__device__ __forceinline__ float* selbuf(int id) {
  switch (id) {
    case 0: return g_x;
    case 1: return g_qk;
    case 2: return g_t;
    case 3: return g_kc;
    case 4: return g_vc;
    default: return g_kvm;
  }
}
__device__ __forceinline__ unsigned short* selbufb(int id) {
  switch (id) {
    case 0: return g_xb;
    case 1: return g_qkb;
    case 2: return g_tb;
    case 3: return g_ffh;
    default: return g_qb;
  }
}

// fp32 -> bf16 (RNE)
__device__ __forceinline__ unsigned short f2b(float x) {
  unsigned int u = __float_as_uint(x);
  u += 0x7FFFu + ((u >> 16) & 1u);
  return (unsigned short)(u >> 16);
}
__device__ __forceinline__ float b2f(unsigned short u) {
  return __uint_as_float(((unsigned int)u) << 16);
}

// ---------------------------------------------------------------------------
__global__ __launch_bounds__(256) void wconv_k(const float* src, int dstoff, int n) {
  int i = blockIdx.x * 256 + threadIdx.x;
  if (i < n) g_wb[dstoff + i] = f2b(src[i]);
}

// ---------------------------------------------------------------------------
// Transpose src [B,D,T] -> g_x [B,T,D] (+ bf16 shadow), or pose -> g_pos.
__global__ __launch_bounds__(256) void trans_in_k(const float* in, int oid) {
  __shared__ float tile[32][33];
  const int tx = threadIdx.x & 31, ty = threadIdx.x >> 5;
  const int t0 = blockIdx.x * 32, d0 = blockIdx.y * 32, b = blockIdx.z;
  #pragma unroll
  for (int i = ty; i < 32; i += 8)
    tile[i][tx] = in[((size_t)(b * Dm + d0 + i)) * Tt + t0 + tx];
  __syncthreads();
  float* out = (oid == 0) ? g_x : g_pos;
  #pragma unroll
  for (int i = ty; i < 32; i += 8) {
    const size_t idx = ((size_t)(b * Tt + t0 + i)) * Dm + d0 + tx;
    float v = tile[tx][i];
    out[idx] = v;
    if (oid == 0) g_xb[idx] = f2b(v);
  }
}

__global__ __launch_bounds__(256) void trans_out_k(float* out) {
  __shared__ float tile[32][33];
  const int tx = threadIdx.x & 31, ty = threadIdx.x >> 5;
  const int t0 = blockIdx.x * 32, d0 = blockIdx.y * 32, b = blockIdx.z;
  #pragma unroll
  for (int i = ty; i < 32; i += 8)
    tile[i][tx] = g_x[((size_t)(b * Tt + t0 + i)) * Dm + d0 + tx];
  __syncthreads();
  #pragma unroll
  for (int i = ty; i < 32; i += 8)
    out[((size_t)(b * Dm + d0 + i)) * Tt + t0 + tx] = tile[tx][i];
}

// g_qkb = bf16(g_x + g_pos)
__global__ __launch_bounds__(256) void addpos_k(int n4) {
  int i = blockIdx.x * 256 + threadIdx.x;
  if (i >= n4) return;
  float4 a = ((const float4*)g_x)[i];
  float4 p = ((const float4*)g_pos)[i];
  short4v v;
  v[0] = (short)f2b(a.x + p.x); v[1] = (short)f2b(a.y + p.y);
  v[2] = (short)f2b(a.z + p.z); v[3] = (short)f2b(a.w + p.w);
  *(short4v*)&g_qkb[(size_t)i * 4] = v;
}

// ---------------------------------------------------------------------------
// MFMA GEMM: C[M,N] = A[M,K](bf16) @ W[N,K](bf16)^T (+bias)(+relu).
// BM=128, BN=64, BK=64; 4 waves (2x2). 1-D grid + bijective XCD
// swizzle; counted-vmcnt 2-deep pipeline; LDS-staged coalesced epilogue.
// DUAL (N=512 merged KQ): n0<256 -> Cid, n0>=256 -> C2id, stride 256.
// PERB: per-batch weights g_wo2 (13 m-blocks x NB per b), guarded stores.
template<int BN, bool DUAL, bool PERB, bool RELU, bool BIAS, bool CBF16>
__global__ __launch_bounds__(256) void gemm2_k(
    int Aid, int woff, const float* __restrict__ bias, int Cid, int C2id,
    int NB, int M, int N, int K) {
  constexpr int BM = 128, BK = 64;
  constexpr int ACH = BM * 8;           // 1024 short8
  constexpr int BCH = BN * 8;           // 512 or 1024
  constexpr int NW = BN / 32;           // n-frags per wave: 2 or 4
  __shared__ short8 As8[2][ACH];
  __shared__ short8 Bs8[2][BCH];
  const int tid = threadIdx.x;
  const int lane = tid & 63, wid = tid >> 6;
  const int wr = wid >> 1, wc = wid & 1;

  // XCD-aware bijective remap (m204).
  const int nwg = gridDim.x;
  const int bid = blockIdx.x;
  const int q = nwg >> 3, r = nwg & 7;
  const int xcd = bid & 7, seq = bid >> 3;
  const int wgid = (xcd < r ? xcd * (q + 1) : r * (q + 1) + (xcd - r) * q) + seq;

  int m0, n0, mlim;
  const unsigned short* W16;
  if constexpr (PERB) {
    const int per = 13 * NB;
    const int b = wgid / per;
    const int rem = wgid - b * per;
    m0 = b * Tt + (rem / NB) * BM;
    n0 = (rem % NB) * BN;
    mlim = b * Tt + Tt;
    W16 = g_wo2 + (size_t)b * 65536;
  } else {
    m0 = (wgid / NB) * BM;
    n0 = (wgid % NB) * BN;
    mlim = M;
    W16 = g_wb + woff;
  }

  const unsigned short* A16 = selbufb(Aid);
  const bool second = DUAL && (n0 >= 256);
  float* Cf = selbuf(second ? C2id : Cid);
  unsigned short* C16 = selbufb(second ? C2id : Cid);
  const int gn0 = second ? n0 - 256 : n0;
  const int cstride = DUAL ? 256 : N;

  f32x4 acc[4][NW];
  #pragma unroll
  for (int m = 0; m < 4; ++m)
    #pragma unroll
    for (int n = 0; n < NW; ++n) acc[m][n] = (f32x4){0.f, 0.f, 0.f, 0.f};

  const int lkc = lane >> 4, lrc = lane & 15;

  auto stage = [&](int t, int buf) {
    const int k0 = t * BK;
    #pragma unroll
    for (int i = 0; i < ACH / 256; ++i) {
      const int c = tid + i * 256;
      const int row = c >> 3, kc = c & 7;
      const unsigned short* gs = A16 + (size_t)(m0 + row) * K + k0 +
                                 ((kc ^ (row & 7)) << 3);
      __builtin_amdgcn_global_load_lds(
          (const __attribute__((address_space(1))) u32*)gs,
          (__attribute__((address_space(3))) u32*)&As8[buf][c], 16, 0, 0);
    }
    #pragma unroll
    for (int i = 0; i < BCH / 256; ++i) {
      const int c = tid + i * 256;
      const int row = c >> 3, kc = c & 7;
      const unsigned short* gs = W16 + (size_t)(n0 + row) * K + k0 +
                                 ((kc ^ (row & 7)) << 3);
      __builtin_amdgcn_global_load_lds(
          (const __attribute__((address_space(1))) u32*)gs,
          (__attribute__((address_space(3))) u32*)&Bs8[buf][c], 16, 0, 0);
    }
  };

  const int nt = K / BK;
  stage(0, 0);
  if (nt > 1) stage(1, 1);
  for (int t = 0; t < nt; ++t) {
    const int cur = t & 1;
    if (t + 1 < nt) {
      if constexpr (BN == 64)
        asm volatile("s_waitcnt vmcnt(6)" ::: "memory");
      else
        asm volatile("s_waitcnt vmcnt(8)" ::: "memory");
    } else {
      asm volatile("s_waitcnt vmcnt(0)" ::: "memory");
    }
    __builtin_amdgcn_sched_barrier(0);
    __builtin_amdgcn_s_barrier();       // buf[cur] visible to all waves
    #pragma unroll
    for (int kk = 0; kk < 2; ++kk) {
      short8 af[4], bf[NW];
      #pragma unroll
      for (int m = 0; m < 4; ++m) {
        const int r2 = wr * 64 + m * 16 + lrc;
        af[m] = As8[cur][r2 * 8 + ((kk * 4 + lkc) ^ (r2 & 7))];
      }
      #pragma unroll
      for (int n = 0; n < NW; ++n) {
        const int cn = wc * (BN / 2) + n * 16 + lrc;
        bf[n] = Bs8[cur][cn * 8 + ((kk * 4 + lkc) ^ (cn & 7))];
      }
      #pragma unroll
      for (int m = 0; m < 4; ++m)
        #pragma unroll
        for (int n = 0; n < NW; ++n)
          acc[m][n] = __builtin_amdgcn_mfma_f32_16x16x32_bf16(
              af[m], bf[n], acc[m][n], 0, 0, 0);
    }
    __builtin_amdgcn_sched_barrier(0);
    __builtin_amdgcn_s_barrier();       // all waves done reading buf[cur]
    __builtin_amdgcn_sched_barrier(0);
    if (t + 2 < nt) stage(t + 2, cur);  // overwrite buf[cur] for t+2
  }

  // ---- LDS-staged epilogue: deposit acc, then coalesced row stores ----
  constexpr int CSTR = (BN == 64) ? BN + 4 : BN;
  float* ldsC = (float*)&As8[0][0];
  {
    asm volatile("s_waitcnt vmcnt(0)" ::: "memory");
    __builtin_amdgcn_s_barrier();
    const int r0 = lkc * 4;
    #pragma unroll
    for (int m = 0; m < 4; ++m)
      #pragma unroll
      for (int n = 0; n < NW; ++n) {
        const int col = wc * (BN / 2) + n * 16 + lrc;
        #pragma unroll
        for (int j = 0; j < 4; ++j)
          ldsC[(wr * 64 + m * 16 + r0 + j) * CSTR + col] = acc[m][n][j];
      }
    __syncthreads();
  }
  if constexpr (CBF16) {
    constexpr int CH = BM * BN / 8;     // short8 chunks
    #pragma unroll
    for (int i = 0; i < CH / 256; ++i) {
      const int c = tid + i * 256;
      const int rowl = c / (BN / 8), col8 = (c % (BN / 8)) * 8;
      if (PERB && m0 + rowl >= mlim) continue;
      short8 v;
      #pragma unroll
      for (int j = 0; j < 8; ++j) {
        float x = ldsC[rowl * CSTR + col8 + j];
        if (BIAS) x += bias[gn0 + col8 + j];
        if (RELU) x = fmaxf(x, 0.f);
        v[j] = (short)f2b(x);
      }
      *(short8*)(C16 + (size_t)(m0 + rowl) * cstride + gn0 + col8) = v;
    }
  } else {
    constexpr int CH = BM * BN / 4;     // float4 chunks
    #pragma unroll
    for (int i = 0; i < CH / 256; ++i) {
      const int c = tid + i * 256;
      const int rowl = c / (BN / 4), col4 = (c % (BN / 4)) * 4;
      if (PERB && m0 + rowl >= mlim) continue;
      float4 v;
      float* pv = &v.x;
      #pragma unroll
      for (int j = 0; j < 4; ++j) {
        float x = ldsC[rowl * CSTR + col4 + j];
        if (BIAS) x += bias[gn0 + col4 + j];
        if (RELU) x = fmaxf(x, 0.f);
        pv[j] = x;
      }
      *(float4*)(Cf + (size_t)(m0 + rowl) * cstride + gn0 + col4) = v;
    }
  }
}

// ---------------------------------------------------------------------------
// K-HALVED GEMM for FF1 (K=256 in two 128-halves): BM=128, BN=128, 8 waves
// (2x4, wave tile 64x32). Single 64 KB LDS buffer -> 2 blocks/CU; cross-
// block TLP overlaps one block's staging with the other's MFMA (the serial
// 128KB K-resident version had 1 block/CU and zero overlap). Accumulation
// order over K identical to the K-resident version (bitwise-same result).
// s_setprio(1) around MFMA: independent blocks at different phases = the
// regime where priority arbitration pays (T5).
template<bool RELU, bool BIAS, bool CBF16>
__global__ __launch_bounds__(512, 4) void gemmh_k(
    int Aid, int woff, const float* __restrict__ bias, int Cid,
    int NB, int M, int N) {
  constexpr int BM = 128, BN = 128, K = 256, KH = 128;
  __shared__ short8 As8[BM * 16];   // 32 KB (one K-half)
  __shared__ short8 Bs8[BN * 16];   // 32 KB
  const int tid = threadIdx.x;
  const int lane = tid & 63, wid = tid >> 6;     // 8 waves
  const int wr = wid >> 2, wc = wid & 3;         // 2 x 4
  const int nwg = gridDim.x;
  const int bid = blockIdx.x;
  const int q = nwg >> 3, r = nwg & 7;
  const int xcd = bid & 7, seq = bid >> 3;
  const int wgid = (xcd < r ? xcd * (q + 1) : r * (q + 1) + (xcd - r) * q) + seq;
  const int m0 = (wgid / NB) * BM, n0 = (wgid % NB) * BN;
  const unsigned short* A16 = selbufb(Aid);
  const unsigned short* W16 = g_wb + woff;
  float* Cf = selbuf(Cid);
  unsigned short* C16 = selbufb(Cid);
  const int lkc = lane >> 4, lrc = lane & 15;

  f32x4 acc[4][2];
  #pragma unroll
  for (int m = 0; m < 4; ++m)
    #pragma unroll
    for (int n = 0; n < 2; ++n) acc[m][n] = (f32x4){0.f, 0.f, 0.f, 0.f};

  #pragma unroll
  for (int h = 0; h < 2; ++h) {
    const int k0 = h * KH;
    if (h) __builtin_amdgcn_s_barrier();   // all waves done reading half 0
    // ---- stage one K-half: 4 + 4 async 16B loads per thread ----
    #pragma unroll
    for (int i = 0; i < (BM * 16) / 512; ++i) {
      const int c = tid + i * 512;
      const int row = c >> 4, kc = c & 15;
      const unsigned short* gs = A16 + (size_t)(m0 + row) * K + k0 +
                                 ((kc ^ (row & 15)) << 3);
      __builtin_amdgcn_global_load_lds(
          (const __attribute__((address_space(1))) u32*)gs,
          (__attribute__((address_space(3))) u32*)&As8[c], 16, 0, 0);
    }
    #pragma unroll
    for (int i = 0; i < (BN * 16) / 512; ++i) {
      const int c = tid + i * 512;
      const int row = c >> 4, kc = c & 15;
      const unsigned short* gs = W16 + (size_t)(n0 + row) * K + k0 +
                                 ((kc ^ (row & 15)) << 3);
      __builtin_amdgcn_global_load_lds(
          (const __attribute__((address_space(1))) u32*)gs,
          (__attribute__((address_space(3))) u32*)&Bs8[c], 16, 0, 0);
    }
    asm volatile("s_waitcnt vmcnt(0)" ::: "memory");
    __builtin_amdgcn_sched_barrier(0);
    __builtin_amdgcn_s_barrier();

    __builtin_amdgcn_s_setprio(1);
    #pragma unroll
    for (int s = 0; s < 4; ++s) {
      short8 af[4], bf[2];
      #pragma unroll
      for (int m = 0; m < 4; ++m) {
        const int r2 = wr * 64 + m * 16 + lrc;
        af[m] = As8[r2 * 16 + ((s * 4 + lkc) ^ (r2 & 15))];
      }
      #pragma unroll
      for (int n = 0; n < 2; ++n) {
        const int cn = wc * 32 + n * 16 + lrc;
        bf[n] = Bs8[cn * 16 + ((s * 4 + lkc) ^ (cn & 15))];
      }
      #pragma unroll
      for (int m = 0; m < 4; ++m)
        #pragma unroll
        for (int n = 0; n < 2; ++n)
          acc[m][n] = __builtin_amdgcn_mfma_f32_16x16x32_bf16(
              af[m], bf[n], acc[m][n], 0, 0, 0);
    }
    __builtin_amdgcn_s_setprio(0);
  }

  // ---- direct epilogue (measured ≈ LDS-staged for this kernel class) ----
  const int r0 = lkc * 4;
  #pragma unroll
  for (int m = 0; m < 4; ++m) {
    const int gmb = m0 + wr * 64 + m * 16 + r0;
    #pragma unroll
    for (int n = 0; n < 2; ++n) {
      const int gn = n0 + wc * 32 + n * 16 + lrc;
      const float bb = BIAS ? bias[gn] : 0.f;
      #pragma unroll
      for (int j = 0; j < 4; ++j) {
        float v = acc[m][n][j] + bb;
        if (RELU) v = fmaxf(v, 0.f);
        if (CBF16) C16[(size_t)(gmb + j) * N + gn] = f2b(v);
        else       Cf[(size_t)(gmb + j) * N + gn] = v;
      }
    }
  }
}

// ---------------------------------------------------------------------------
// Conv compression (tc = 1..800) + edge rows (j=0 null, j=1 bias) in block 0.
__global__ __launch_bounds__(256) void compress_main_k(
    const float* __restrict__ cw, const float* __restrict__ cb,
    const float* __restrict__ nul, int out_id) {
  __shared__ float rows[32][256];       // 32 KB
  const int tc0 = 1 + blockIdx.x * 16;
  const int b = blockIdx.y;
  const int tid = threadIdx.x;
  const int o = tid;
  const int g = o >> 5;

  const int r0g = 2 * tc0 - 2;
  const unsigned short* src = g_tb + ((size_t)b * Tt + r0g) * Dm;
  #pragma unroll
  for (int i = 0; i < 4; ++i) {
    const int c = tid + i * 256;        // 1024 chunks of 8
    const int row = c >> 5, off = (c & 31) * 8;
    short8 v = *(const short8*)(src + (size_t)row * 256 + off);
    #pragma unroll
    for (int j = 0; j < 8; ++j)
      rows[row][off + j] = b2f((unsigned short)v[j]);
  }

  float we[32], wo[32];
  {
    const float4* wp = (const float4*)(cw + o * 64);
    #pragma unroll
    for (int i = 0; i < 16; ++i) {
      float4 w4 = wp[i];
      we[i * 2 + 0] = w4.x; wo[i * 2 + 0] = w4.y;
      we[i * 2 + 1] = w4.z; wo[i * 2 + 1] = w4.w;
    }
  }
  const float bias = cb[o];
  float* outb = selbuf(out_id) + (size_t)b * Tkv * Dm;
  if (blockIdx.x == 0) {                // edge rows j=0,1
    outb[o] = nul[b * Dm + o];
    outb[Dm + o] = bias;
  }
  __syncthreads();

  float* outp = outb + o;
  #pragma unroll
  for (int t = 0; t < 16; ++t) {
    const int lr = 2 * t;
    const float* p0 = &rows[lr][g * 32];
    const float* p1 = &rows[lr + 1][g * 32];
    float acc = bias;
    #pragma unroll
    for (int i4 = 0; i4 < 8; ++i4) {
      float4 a0 = *(const float4*)(p0 + i4 * 4);
      float4 a1 = *(const float4*)(p1 + i4 * 4);
      acc = fmaf(we[i4 * 4 + 0], a0.x, acc);
      acc = fmaf(we[i4 * 4 + 1], a0.y, acc);
      acc = fmaf(we[i4 * 4 + 2], a0.z, acc);
      acc = fmaf(we[i4 * 4 + 3], a0.w, acc);
      acc = fmaf(wo[i4 * 4 + 0], a1.x, acc);
      acc = fmaf(wo[i4 * 4 + 1], a1.y, acc);
      acc = fmaf(wo[i4 * 4 + 2], a1.z, acc);
      acc = fmaf(wo[i4 * 4 + 3], a1.w, acc);
    }
    outp[(size_t)(1 + tc0 + t) * Dm] = acc;
  }
}

// ---------------------------------------------------------------------------
// KV reduction stage 1/2 (validated).
__global__ __launch_bounds__(256) void kvout1_k() {
  __shared__ float kl[8][32];
  __shared__ float vl[8][32];
  const int bh = blockIdx.x;
  const int js = blockIdx.y;
  const int b = bh >> 3, h = bh & 7;
  const int j0 = js * 101;
  const int jend = (j0 + 101 < Tkv) ? j0 + 101 : Tkv;

  const int tid = threadIdx.x;
  const int lr = tid >> 5;
  const int lc = tid & 31;
  const int e = tid >> 3;
  const int d0 = (tid & 7) * 4;

  float a0 = 0.f, a1 = 0.f, a2 = 0.f, a3 = 0.f;
  const size_t base = (size_t)b * Tkv * Dm + h * 32;

  for (int jc = j0; jc < jend; jc += 8) {
    const int jr = jc + lr;
    if (jr < jend) {
      kl[lr][lc] = g_kc[base + (size_t)jr * Dm + lc];
      vl[lr][lc] = g_vc[base + (size_t)jr * Dm + lc];
    } else {
      kl[lr][lc] = 0.f;
      vl[lr][lc] = 0.f;
    }
    __syncthreads();
    #pragma unroll
    for (int r = 0; r < 8; ++r) {
      const float kf = kl[r][e];
      const float* vr = &vl[r][d0];
      a0 = fmaf(kf, vr[0], a0);
      a1 = fmaf(kf, vr[1], a1);
      a2 = fmaf(kf, vr[2], a2);
      a3 = fmaf(kf, vr[3], a3);
    }
    __syncthreads();
  }
  float* op = g_kvp + ((size_t)js * 80 + bh) * 1024 + e * 32 + d0;
  op[0] = a0; op[1] = a1; op[2] = a2; op[3] = a3;
}

__global__ __launch_bounds__(256) void kvout2_k() {
  const int bh = blockIdx.x;
  const int tid = threadIdx.x;
  const int e = tid >> 3;
  const int d0 = (tid & 7) * 4;
  float a0 = 0.f, a1 = 0.f, a2 = 0.f, a3 = 0.f;
  #pragma unroll
  for (int s = 0; s < JCH; ++s) {
    const float* p = g_kvp + ((size_t)s * 80 + bh) * 1024 + e * 32 + d0;
    a0 += p[0]; a1 += p[1]; a2 += p[2]; a3 += p[3];
  }
  float* op = g_kvm + (size_t)bh * 1024 + e * 32 + d0;
  op[0] = a0 * 0.0625f;
  op[1] = a1 * 0.0625f;
  op[2] = a2 * 0.0625f;
  op[3] = a3 * 0.0625f;
}

// ---------------------------------------------------------------------------
// W'[b,n,h*32+e] = sum_d kvm[b,h,e,d] * Wo[n,h*32+d]   (bf16 out)
__global__ __launch_bounds__(256) void wo2_k(int wooff) {
  const int n = blockIdx.x, b = blockIdx.y;
  const int he = threadIdx.x;
  const int h = he >> 5, e = he & 31;
  const float* kp = g_kvm + ((size_t)(b * Hh + h) * 32 + e) * 32;
  const unsigned short* wp = g_wb + wooff + (size_t)n * Dm + h * 32;
  float acc = 0.f;
  #pragma unroll
  for (int d = 0; d < 32; ++d) acc = fmaf(kp[d], b2f(wp[d]), acc);
  g_wo2[(size_t)b * 65536 + (size_t)n * Dm + he] = f2b(acc);
}

// ---------------------------------------------------------------------------
// x = LN(x + delta)*g + beta (fp32), writes bf16 shadow g_xb.
// If do_pos: also writes g_qkb = bf16(ln_out + pos).
__global__ __launch_bounds__(256) void ln_k(int did, const float* g,
                                            const float* beta, int do_pos) {
  const int lane = threadIdx.x & 63;
  const int wave = threadIdx.x >> 6;
  const size_t row = (size_t)blockIdx.x * 4 + wave;
  float4 xv = ((const float4*)g_x)[row * 64 + lane];
  float4 dv = ((const float4*)selbuf(did))[row * 64 + lane];
  float v[4] = {xv.x + dv.x, xv.y + dv.y, xv.z + dv.z, xv.w + dv.w};
  float sum = v[0] + v[1] + v[2] + v[3];
  float sq = v[0]*v[0] + v[1]*v[1] + v[2]*v[2] + v[3]*v[3];
  #pragma unroll
  for (int off = 32; off; off >>= 1) {
    sum += __shfl_xor(sum, off);
    sq  += __shfl_xor(sq, off);
  }
  const float mean = sum * (1.f / 256.f);
  const float var = sq * (1.f / 256.f) - mean * mean;
  const float rs = rsqrtf(var + 1e-5f);
  float4 gg = ((const float4*)g)[lane];
  float4 bb = ((const float4*)beta)[lane];
  float4 ov;
  ov.x = (v[0] - mean) * rs * gg.x + bb.x;
  ov.y = (v[1] - mean) * rs * gg.y + bb.y;
  ov.z = (v[2] - mean) * rs * gg.z + bb.z;
  ov.w = (v[3] - mean) * rs * gg.w + bb.w;
  ((float4*)g_x)[row * 64 + lane] = ov;
  short4v sv;
  sv[0] = (short)f2b(ov.x); sv[1] = (short)f2b(ov.y);
  sv[2] = (short)f2b(ov.z); sv[3] = (short)f2b(ov.w);
  *(short4v*)&g_xb[(row * 64 + lane) * 4] = sv;
  if (do_pos) {
    float4 pv = ((const float4*)g_pos)[row * 64 + lane];
    short4v qv;
    qv[0] = (short)f2b(ov.x + pv.x); qv[1] = (short)f2b(ov.y + pv.y);
    qv[2] = (short)f2b(ov.z + pv.z); qv[3] = (short)f2b(ov.w + pv.w);
    *(short4v*)&g_qkb[(row * 64 + lane) * 4] = qv;
  }
}

// ---------------------------------------------------------------------------
extern "C" void kernel_launch(void* const* d_in, const int* in_sizes, int n_in,
                              void* d_out, int out_size, void* d_ws, size_t ws_size,
                              hipStream_t stream) {
  const float* src  = (const float*)d_in[0];
  const float* pose = (const float*)d_in[1];
  const float* Wq   = (const float*)d_in[2];
  const float* Wk   = (const float*)d_in[3];
  const float* Wv   = (const float*)d_in[4];
  const float* Wo   = (const float*)d_in[5];
  const float* bo   = (const float*)d_in[6];
  const float* cw   = (const float*)d_in[7];
  const float* cb   = (const float*)d_in[8];
  const float* nk   = (const float*)d_in[9];
  const float* nv   = (const float*)d_in[10];
  const float* ln1g = (const float*)d_in[11];
  const float* ln1b = (const float*)d_in[12];
  const float* ln2g = (const float*)d_in[13];
  const float* ln2b = (const float*)d_in[14];
  const float* W1   = (const float*)d_in[15];
  const float* b1   = (const float*)d_in[16];
  const float* W2   = (const float*)d_in[17];
  const float* b2   = (const float*)d_in[18];

  const int MT = Bsz * Tt;        // 16000
  const int NF = (int)Fsz;        // 4,096,000
  const dim3 tgrid(Tt / 32, Dm / 32, Bsz);

  // g_wb layout: per-layer [Wk|Wq] at l*131072; then Wv, Wo, W1, W2.
  const int OV = 262144, OO = 393216, O1 = 524288, O2 = 1572864;
  for (int l = 0; l < 2; ++l) {
    wconv_k<<<256, 256, 0, stream>>>(Wk + (size_t)l * 65536, l * 131072, 65536);
    wconv_k<<<256, 256, 0, stream>>>(Wq + (size_t)l * 65536, l * 131072 + 65536, 65536);
    wconv_k<<<256, 256, 0, stream>>>(Wv + (size_t)l * 65536, OV + l * 65536, 65536);
    wconv_k<<<256, 256, 0, stream>>>(Wo + (size_t)l * 65536, OO + l * 65536, 65536);
  }
  wconv_k<<<4096, 256, 0, stream>>>(W1, O1, 1048576);
  wconv_k<<<4096, 256, 0, stream>>>(W2, O2, 1048576);

  trans_in_k<<<tgrid, 256, 0, stream>>>(src, 0);    // writes g_x + g_xb
  trans_in_k<<<tgrid, 256, 0, stream>>>(pose, 7);

  const int MB = MT / 128;  // 125 m-blocks
  for (int l = 0; l < 2; ++l) {
    const float* bo_l = bo + (size_t)l * Dm;
    const float* cw_l = cw + (size_t)l * Dm * 64;
    const float* cb_l = cb + (size_t)l * Dm;
    const float* nk_l = nk + (size_t)l * Bsz * Dm;
    const float* nv_l = nv + (size_t)l * Bsz * Dm;
    const float* b1_l = b1 + (size_t)l * FFd;
    const float* b2_l = b2 + (size_t)l * Dm;
    const int wkq = l * 131072;
    const int wv = OV + l * 65536, wo = OO + l * 65536;
    const int w1 = O1 + l * 524288, w2 = O2 + l * 524288;

    // qkb = bf16(x + pos): layer 0 explicit; layer 1 from fused LN2.
    if (l == 0) addpos_k<<<NF / 4 / 256, 256, 0, stream>>>(NF / 4);
    // [k|q] = qkb @ [Wk|Wq]^T : k -> tb, q -> qb (N=512 dual-dest, NB=8)
    gemm2_k<64, true, false, false, false, true><<<8 * MB, 256, 0, stream>>>(
        1, wkq, nullptr, 2, 4, 8, MT, 512, Dm);
    compress_main_k<<<dim3(50, Bsz), 256, 0, stream>>>(cw_l, cb_l, nk_l, 3);
    // v = xb @ Wv^T -> tb ; compress -> vc  (NB=4)
    gemm2_k<64, false, false, false, false, true><<<4 * MB, 256, 0, stream>>>(
        0, wv, nullptr, 2, 2, 4, MT, Dm, Dm);
    compress_main_k<<<dim3(50, Bsz), 256, 0, stream>>>(cw_l, cb_l, nv_l, 4);
    // kvm = (1/16) kc^T vc
    kvout1_k<<<dim3(Bsz * Hh, JCH), 256, 0, stream>>>();
    kvout2_k<<<Bsz * Hh, 256, 0, stream>>>();
    // W' = kvm (×) Wo  (per-b fused attn+Wo weights)
    wo2_k<<<dim3(Dm, Bsz), 256, 0, stream>>>(wo);
    // t = qb @ W'^T + bo (fp32, per-b) ; x = LN(x + t)
    gemm2_k<64, false, true, false, true, false><<<Bsz * 13 * 4, 256, 0, stream>>>(
        4, 0, bo_l, 2, 2, 4, MT, Dm, Dm);
    ln_k<<<MT / 4, 256, 0, stream>>>(2, ln1g + l * Dm, ln1b + l * Dm, 0);

    // FF1: ffh = bf16(relu(xb @ W1^T + b1))  [K-halved, 64KB LDS, grid 2000]
    gemmh_k<true, true, true><<<16 * MB, 512, 0, stream>>>(
        0, w1, b1_l, 3, 16, MT, FFd);
    // FF2: qk = ffh @ W2^T + b2 (fp32)  [BN=64, NB=4, grid 500]
    gemm2_k<64, false, false, false, true, false><<<4 * MB, 256, 0, stream>>>(
        3, w2, b2_l, 1, 1, 4, MT, Dm, FFd);
    // LN2: layer 0 fused with next layer's pos-add (writes qkb).
    ln_k<<<MT / 4, 256, 0, stream>>>(1, ln2g + l * Dm, ln2b + l * Dm,
                                     l == 0 ? 1 : 0);
  }

  trans_out_k<<<tgrid, 256, 0, stream>>>((float*)d_out);
}

// Round 3
// 385.208 us; speedup vs baseline: 1.1754x; 1.0628x over previous
//
#include <hip/hip_runtime.h>
#include <math.h>

typedef __attribute__((ext_vector_type(8))) short short8;   // 8 bf16
typedef __attribute__((ext_vector_type(4))) short short4v;  // 4 bf16
typedef __attribute__((ext_vector_type(4))) float f32x4;
typedef unsigned int u32;

constexpr int Bsz = 10;
constexpr int Dm  = 256;
constexpr int Hh  = 8;
constexpr int Tt  = 1600;
constexpr int FFd = 2048;
constexpr int Tkv = 802;   // 1 null + 801 compressed
constexpr int JCH = 8;     // j-splits for kv reduction
constexpr size_t Fsz  = (size_t)Bsz * Tt * Dm;    // 4,096,000
constexpr size_t PAD  = 65536;
constexpr size_t KVsz = (size_t)Bsz * Tkv * Dm;   // 2,053,120
constexpr size_t FHsz = (size_t)Bsz * Tt * FFd;   // 32,768,000
constexpr size_t WBsz = 2621440;                  // all weights, bf16

// Static device scratch; referenced ONLY from device code.
__device__ float g_x[Fsz];                        // residual stream fp32
__device__ float g_qk[Fsz];                       // FF2 k-half0 out (LN2 d1)
__device__ float g_t[Fsz];                        // Wo out / FF2 k-half1 (LN2 d2)
__device__ float g_kc[KVsz];                      // compressed K
__device__ float g_vc[KVsz];                      // compressed V
__device__ float g_kvm[(size_t)Bsz * Hh * 32 * 32];
__device__ float g_kvp[(size_t)JCH * Bsz * Hh * 32 * 32];
__device__ float g_pos[Fsz];                      // transposed pos fp32
__device__ unsigned short g_xb[Fsz + PAD];        // bf16 shadow of x
__device__ unsigned short g_qkb[Fsz + PAD];       // bf16 x+pos
__device__ unsigned short g_tb[Fsz + PAD];        // bf16 k projection
__device__ unsigned short g_qb[Fsz + PAD];        // bf16 q projection
__device__ unsigned short g_ffh[FHsz + PAD];      // bf16 FF hidden / v proj
__device__ unsigned short g_wb[WBsz];             // bf16 weights
__device__ unsigned short g_wo2[(size_t)Bsz * Dm * Dm];  // per-b fused kvm*Wo

__device__ __forceinline__ float* selbuf(int id) {
  switch (id) {
    case 0: return g_x;
    case 1: return g_qk;
    case 2: return g_t;
    case 3: return g_kc;
    case 4: return g_vc;
    default: return g_kvm;
  }
}
__device__ __forceinline__ unsigned short* selbufb(int id) {
  switch (id) {
    case 0: return g_xb;
    case 1: return g_qkb;
    case 2: return g_tb;
    case 3: return g_ffh;
    default: return g_qb;
  }
}

// fp32 -> bf16 (RNE)
__device__ __forceinline__ unsigned short f2b(float x) {
  unsigned int u = __float_as_uint(x);
  u += 0x7FFFu + ((u >> 16) & 1u);
  return (unsigned short)(u >> 16);
}
__device__ __forceinline__ float b2f(unsigned short u) {
  return __uint_as_float(((unsigned int)u) << 16);
}

// ---------------------------------------------------------------------------
// ALL weight conversions in one dispatch. g_wb layout:
// [l0:Wk|Wq][l1:Wk|Wq] | Wv(l0,l1) | Wo(l0,l1) | W1(l0,l1) | W2(l0,l1)
__global__ __launch_bounds__(256) void wconv_all_k(
    const float* __restrict__ Wk, const float* __restrict__ Wq,
    const float* __restrict__ Wv, const float* __restrict__ Wo,
    const float* __restrict__ W1, const float* __restrict__ W2) {
  const int i = blockIdx.x * 256 + threadIdx.x;   // < 2,621,440
  float v;
  if (i < 262144) {
    const int l = i >> 17, r = i & 131071;
    v = (r < 65536) ? Wk[l * 65536 + r] : Wq[l * 65536 + (r - 65536)];
  } else if (i < 393216) {
    v = Wv[i - 262144];
  } else if (i < 524288) {
    v = Wo[i - 393216];
  } else if (i < 1572864) {
    v = W1[i - 524288];
  } else {
    v = W2[i - 1572864];
  }
  g_wb[i] = f2b(v);
}

// ---------------------------------------------------------------------------
// Fused input transpose + pos-add: src,pose [B,D,T] -> g_x, g_xb, g_pos,
// g_qkb = bf16(x+pos). Replaces trans_in x2 + addpos (saves 33 MB re-read).
__global__ __launch_bounds__(256) void trans_in2_k(const float* __restrict__ src,
                                                   const float* __restrict__ pose) {
  __shared__ float ts[32][33];
  __shared__ float tp[32][33];
  const int tx = threadIdx.x & 31, ty = threadIdx.x >> 5;
  const int t0 = blockIdx.x * 32, d0 = blockIdx.y * 32, b = blockIdx.z;
  #pragma unroll
  for (int i = ty; i < 32; i += 8) {
    const size_t gi = ((size_t)(b * Dm + d0 + i)) * Tt + t0 + tx;
    ts[i][tx] = src[gi];
    tp[i][tx] = pose[gi];
  }
  __syncthreads();
  #pragma unroll
  for (int i = ty; i < 32; i += 8) {
    const size_t idx = ((size_t)(b * Tt + t0 + i)) * Dm + d0 + tx;
    const float s = ts[tx][i], p = tp[tx][i];
    g_x[idx] = s;
    g_pos[idx] = p;
    g_xb[idx] = f2b(s);
    g_qkb[idx] = f2b(s + p);
  }
}

__global__ __launch_bounds__(256) void trans_out_k(float* out) {
  __shared__ float tile[32][33];
  const int tx = threadIdx.x & 31, ty = threadIdx.x >> 5;
  const int t0 = blockIdx.x * 32, d0 = blockIdx.y * 32, b = blockIdx.z;
  #pragma unroll
  for (int i = ty; i < 32; i += 8)
    tile[i][tx] = g_x[((size_t)(b * Tt + t0 + i)) * Dm + d0 + tx];
  __syncthreads();
  #pragma unroll
  for (int i = ty; i < 32; i += 8)
    out[((size_t)(b * Dm + d0 + i)) * Tt + t0 + tx] = tile[tx][i];
}

// ---------------------------------------------------------------------------
// MFMA GEMM: C[M,N] = A[M,K](bf16) @ W[N,K](bf16)^T (+bias)(+relu).
// BM=128, BN=64, BK=64; 4 waves (2x2). 1-D grid + bijective XCD
// swizzle; counted-vmcnt 2-deep pipeline; LDS-staged coalesced epilogue.
// DUAL (N=512 merged KQ): n0<256 -> Cid, n0>=256 -> C2id, stride 256.
// PERB: per-batch weights g_wo2 (13 m-blocks x NB per b), guarded stores.
template<int BN, bool DUAL, bool PERB, bool RELU, bool BIAS, bool CBF16>
__global__ __launch_bounds__(256) void gemm2_k(
    int Aid, int woff, const float* __restrict__ bias, int Cid, int C2id,
    int NB, int M, int N, int K) {
  constexpr int BM = 128, BK = 64;
  constexpr int ACH = BM * 8;           // 1024 short8
  constexpr int BCH = BN * 8;           // 512 or 1024
  constexpr int NW = BN / 32;           // n-frags per wave: 2 or 4
  __shared__ short8 As8[2][ACH];
  __shared__ short8 Bs8[2][BCH];
  const int tid = threadIdx.x;
  const int lane = tid & 63, wid = tid >> 6;
  const int wr = wid >> 1, wc = wid & 1;

  // XCD-aware bijective remap (m204).
  const int nwg = gridDim.x;
  const int bid = blockIdx.x;
  const int q = nwg >> 3, r = nwg & 7;
  const int xcd = bid & 7, seq = bid >> 3;
  const int wgid = (xcd < r ? xcd * (q + 1) : r * (q + 1) + (xcd - r) * q) + seq;

  int m0, n0, mlim;
  const unsigned short* W16;
  if constexpr (PERB) {
    const int per = 13 * NB;
    const int b = wgid / per;
    const int rem = wgid - b * per;
    m0 = b * Tt + (rem / NB) * BM;
    n0 = (rem % NB) * BN;
    mlim = b * Tt + Tt;
    W16 = g_wo2 + (size_t)b * 65536;
  } else {
    m0 = (wgid / NB) * BM;
    n0 = (wgid % NB) * BN;
    mlim = M;
    W16 = g_wb + woff;
  }

  const unsigned short* A16 = selbufb(Aid);
  const bool second = DUAL && (n0 >= 256);
  float* Cf = selbuf(second ? C2id : Cid);
  unsigned short* C16 = selbufb(second ? C2id : Cid);
  const int gn0 = second ? n0 - 256 : n0;
  const int cstride = DUAL ? 256 : N;

  f32x4 acc[4][NW];
  #pragma unroll
  for (int m = 0; m < 4; ++m)
    #pragma unroll
    for (int n = 0; n < NW; ++n) acc[m][n] = (f32x4){0.f, 0.f, 0.f, 0.f};

  const int lkc = lane >> 4, lrc = lane & 15;

  auto stage = [&](int t, int buf) {
    const int k0 = t * BK;
    #pragma unroll
    for (int i = 0; i < ACH / 256; ++i) {
      const int c = tid + i * 256;
      const int row = c >> 3, kc = c & 7;
      const unsigned short* gs = A16 + (size_t)(m0 + row) * K + k0 +
                                 ((kc ^ (row & 7)) << 3);
      __builtin_amdgcn_global_load_lds(
          (const __attribute__((address_space(1))) u32*)gs,
          (__attribute__((address_space(3))) u32*)&As8[buf][c], 16, 0, 0);
    }
    #pragma unroll
    for (int i = 0; i < BCH / 256; ++i) {
      const int c = tid + i * 256;
      const int row = c >> 3, kc = c & 7;
      const unsigned short* gs = W16 + (size_t)(n0 + row) * K + k0 +
                                 ((kc ^ (row & 7)) << 3);
      __builtin_amdgcn_global_load_lds(
          (const __attribute__((address_space(1))) u32*)gs,
          (__attribute__((address_space(3))) u32*)&Bs8[buf][c], 16, 0, 0);
    }
  };

  const int nt = K / BK;
  stage(0, 0);
  if (nt > 1) stage(1, 1);
  for (int t = 0; t < nt; ++t) {
    const int cur = t & 1;
    if (t + 1 < nt) {
      if constexpr (BN == 64)
        asm volatile("s_waitcnt vmcnt(6)" ::: "memory");
      else
        asm volatile("s_waitcnt vmcnt(8)" ::: "memory");
    } else {
      asm volatile("s_waitcnt vmcnt(0)" ::: "memory");
    }
    __builtin_amdgcn_sched_barrier(0);
    __builtin_amdgcn_s_barrier();       // buf[cur] visible to all waves
    #pragma unroll
    for (int kk = 0; kk < 2; ++kk) {
      short8 af[4], bf[NW];
      #pragma unroll
      for (int m = 0; m < 4; ++m) {
        const int r2 = wr * 64 + m * 16 + lrc;
        af[m] = As8[cur][r2 * 8 + ((kk * 4 + lkc) ^ (r2 & 7))];
      }
      #pragma unroll
      for (int n = 0; n < NW; ++n) {
        const int cn = wc * (BN / 2) + n * 16 + lrc;
        bf[n] = Bs8[cur][cn * 8 + ((kk * 4 + lkc) ^ (cn & 7))];
      }
      #pragma unroll
      for (int m = 0; m < 4; ++m)
        #pragma unroll
        for (int n = 0; n < NW; ++n)
          acc[m][n] = __builtin_amdgcn_mfma_f32_16x16x32_bf16(
              af[m], bf[n], acc[m][n], 0, 0, 0);
    }
    __builtin_amdgcn_sched_barrier(0);
    __builtin_amdgcn_s_barrier();       // all waves done reading buf[cur]
    __builtin_amdgcn_sched_barrier(0);
    if (t + 2 < nt) stage(t + 2, cur);  // overwrite buf[cur] for t+2
  }

  // ---- LDS-staged epilogue: deposit acc, then coalesced row stores ----
  constexpr int CSTR = (BN == 64) ? BN + 4 : BN;
  float* ldsC = (float*)&As8[0][0];
  {
    asm volatile("s_waitcnt vmcnt(0)" ::: "memory");
    __builtin_amdgcn_s_barrier();
    const int r0 = lkc * 4;
    #pragma unroll
    for (int m = 0; m < 4; ++m)
      #pragma unroll
      for (int n = 0; n < NW; ++n) {
        const int col = wc * (BN / 2) + n * 16 + lrc;
        #pragma unroll
        for (int j = 0; j < 4; ++j)
          ldsC[(wr * 64 + m * 16 + r0 + j) * CSTR + col] = acc[m][n][j];
      }
    __syncthreads();
  }
  if constexpr (CBF16) {
    constexpr int CH = BM * BN / 8;     // short8 chunks
    #pragma unroll
    for (int i = 0; i < CH / 256; ++i) {
      const int c = tid + i * 256;
      const int rowl = c / (BN / 8), col8 = (c % (BN / 8)) * 8;
      if (PERB && m0 + rowl >= mlim) continue;
      short8 v;
      #pragma unroll
      for (int j = 0; j < 8; ++j) {
        float x = ldsC[rowl * CSTR + col8 + j];
        if (BIAS) x += bias[gn0 + col8 + j];
        if (RELU) x = fmaxf(x, 0.f);
        v[j] = (short)f2b(x);
      }
      *(short8*)(C16 + (size_t)(m0 + rowl) * cstride + gn0 + col8) = v;
    }
  } else {
    constexpr int CH = BM * BN / 4;     // float4 chunks
    #pragma unroll
    for (int i = 0; i < CH / 256; ++i) {
      const int c = tid + i * 256;
      const int rowl = c / (BN / 4), col4 = (c % (BN / 4)) * 4;
      if (PERB && m0 + rowl >= mlim) continue;
      float4 v;
      float* pv = &v.x;
      #pragma unroll
      for (int j = 0; j < 4; ++j) {
        float x = ldsC[rowl * CSTR + col4 + j];
        if (BIAS) x += bias[gn0 + col4 + j];
        if (RELU) x = fmaxf(x, 0.f);
        pv[j] = x;
      }
      *(float4*)(Cf + (size_t)(m0 + rowl) * cstride + gn0 + col4) = v;
    }
  }
}

// ---------------------------------------------------------------------------
// N-RESIDENT GEMM for FF2: BM=128, full N=256 per block, K split in two
// halves (grid = 2 x 125). ks=0 -> g_qk (+bias), ks=1 -> g_t; ln2 sums both.
// 8 waves (2x4), wave tile 64x64, acc 64 VGPR. Total staged bytes drop
// 393 MB -> 128 MB (A staged once, W2 staged once). Same counted-vmcnt
// 2-deep pipeline as gemm2_k; 96 KB LDS -> 1 block/CU.
__global__ __launch_bounds__(512, 2) void gemmn_k(
    int Aid, int woff, const float* __restrict__ bias, int K) {
  constexpr int BM = 128, BN = 256, BK = 64;
  constexpr int ACH = BM * 8;           // 1024 short8 (16 KB)
  constexpr int BCH = BN * 8;           // 2048 short8 (32 KB)
  __shared__ short8 As8[2][ACH];
  __shared__ short8 Bs8[2][BCH];
  const int tid = threadIdx.x;
  const int lane = tid & 63, wid = tid >> 6;     // 8 waves
  const int wr = wid >> 2, wc = wid & 3;         // 2 x 4
  const int nwg = gridDim.x, bid = blockIdx.x;
  const int q = nwg >> 3, r = nwg & 7;
  const int xcd = bid & 7, seq = bid >> 3;
  const int wgid = (xcd < r ? xcd * (q + 1) : r * (q + 1) + (xcd - r) * q) + seq;
  const int half = nwg >> 1;            // 125 m-blocks per k-half
  const int ks = (wgid >= half) ? 1 : 0;
  const int m0 = (wgid - ks * half) * BM;
  const int kbase = ks * (K >> 1);
  const unsigned short* A16 = selbufb(Aid);
  const unsigned short* W16 = g_wb + woff;
  float* Cf = ks ? g_t : g_qk;

  f32x4 acc[4][4];
  #pragma unroll
  for (int m = 0; m < 4; ++m)
    #pragma unroll
    for (int n = 0; n < 4; ++n) acc[m][n] = (f32x4){0.f, 0.f, 0.f, 0.f};

  const int lkc = lane >> 4, lrc = lane & 15;

  auto stage = [&](int t, int buf) {
    const int k0 = kbase + t * BK;
    #pragma unroll
    for (int i = 0; i < ACH / 512; ++i) {        // 2 / thread
      const int c = tid + i * 512;
      const int row = c >> 3, kc = c & 7;
      const unsigned short* gs = A16 + (size_t)(m0 + row) * K + k0 +
                                 ((kc ^ (row & 7)) << 3);
      __builtin_amdgcn_global_load_lds(
          (const __attribute__((address_space(1))) u32*)gs,
          (__attribute__((address_space(3))) u32*)&As8[buf][c], 16, 0, 0);
    }
    #pragma unroll
    for (int i = 0; i < BCH / 512; ++i) {        // 4 / thread
      const int c = tid + i * 512;
      const int row = c >> 3, kc = c & 7;
      const unsigned short* gs = W16 + (size_t)row * K + k0 +
                                 ((kc ^ (row & 7)) << 3);
      __builtin_amdgcn_global_load_lds(
          (const __attribute__((address_space(1))) u32*)gs,
          (__attribute__((address_space(3))) u32*)&Bs8[buf][c], 16, 0, 0);
    }
  };

  const int nt = (K >> 1) / BK;   // 16
  stage(0, 0);
  stage(1, 1);
  for (int t = 0; t < nt; ++t) {
    const int cur = t & 1;
    if (t + 1 < nt) asm volatile("s_waitcnt vmcnt(6)" ::: "memory");
    else            asm volatile("s_waitcnt vmcnt(0)" ::: "memory");
    __builtin_amdgcn_sched_barrier(0);
    __builtin_amdgcn_s_barrier();       // buf[cur] visible to all waves
    #pragma unroll
    for (int kk = 0; kk < 2; ++kk) {
      short8 af[4], bf[4];
      #pragma unroll
      for (int m = 0; m < 4; ++m) {
        const int r2 = wr * 64 + m * 16 + lrc;
        af[m] = As8[cur][r2 * 8 + ((kk * 4 + lkc) ^ (r2 & 7))];
      }
      #pragma unroll
      for (int n = 0; n < 4; ++n) {
        const int cn = wc * 64 + n * 16 + lrc;
        bf[n] = Bs8[cur][cn * 8 + ((kk * 4 + lkc) ^ (cn & 7))];
      }
      #pragma unroll
      for (int m = 0; m < 4; ++m)
        #pragma unroll
        for (int n = 0; n < 4; ++n)
          acc[m][n] = __builtin_amdgcn_mfma_f32_16x16x32_bf16(
              af[m], bf[n], acc[m][n], 0, 0, 0);
    }
    __builtin_amdgcn_sched_barrier(0);
    __builtin_amdgcn_s_barrier();       // all waves done reading buf[cur]
    __builtin_amdgcn_sched_barrier(0);
    if (t + 2 < nt) stage(t + 2, cur);
  }

  // ---- direct fp32 epilogue ----
  const int r0 = lkc * 4;
  #pragma unroll
  for (int m = 0; m < 4; ++m) {
    const int gm = m0 + wr * 64 + m * 16 + r0;
    #pragma unroll
    for (int n = 0; n < 4; ++n) {
      const int gn = wc * 64 + n * 16 + lrc;
      const float bb = (ks == 0) ? bias[gn] : 0.f;
      #pragma unroll
      for (int j = 0; j < 4; ++j)
        Cf[(size_t)(gm + j) * BN + gn] = acc[m][n][j] + bb;
    }
  }
}

// ---------------------------------------------------------------------------
// K-HALVED GEMM for FF1 (K=256 in two 128-halves): BM=128, BN=128, 8 waves
// (2x4, wave tile 64x32). Single 64 KB LDS buffer -> 2 blocks/CU; cross-
// block TLP overlaps one block's staging with the other's MFMA.
template<bool RELU, bool BIAS, bool CBF16>
__global__ __launch_bounds__(512, 4) void gemmh_k(
    int Aid, int woff, const float* __restrict__ bias, int Cid,
    int NB, int M, int N) {
  constexpr int BM = 128, BN = 128, K = 256, KH = 128;
  __shared__ short8 As8[BM * 16];   // 32 KB (one K-half)
  __shared__ short8 Bs8[BN * 16];   // 32 KB
  const int tid = threadIdx.x;
  const int lane = tid & 63, wid = tid >> 6;     // 8 waves
  const int wr = wid >> 2, wc = wid & 3;         // 2 x 4
  const int nwg = gridDim.x;
  const int bid = blockIdx.x;
  const int q = nwg >> 3, r = nwg & 7;
  const int xcd = bid & 7, seq = bid >> 3;
  const int wgid = (xcd < r ? xcd * (q + 1) : r * (q + 1) + (xcd - r) * q) + seq;
  const int m0 = (wgid / NB) * BM, n0 = (wgid % NB) * BN;
  const unsigned short* A16 = selbufb(Aid);
  const unsigned short* W16 = g_wb + woff;
  float* Cf = selbuf(Cid);
  unsigned short* C16 = selbufb(Cid);
  const int lkc = lane >> 4, lrc = lane & 15;

  f32x4 acc[4][2];
  #pragma unroll
  for (int m = 0; m < 4; ++m)
    #pragma unroll
    for (int n = 0; n < 2; ++n) acc[m][n] = (f32x4){0.f, 0.f, 0.f, 0.f};

  #pragma unroll
  for (int h = 0; h < 2; ++h) {
    const int k0 = h * KH;
    if (h) __builtin_amdgcn_s_barrier();   // all waves done reading half 0
    #pragma unroll
    for (int i = 0; i < (BM * 16) / 512; ++i) {
      const int c = tid + i * 512;
      const int row = c >> 4, kc = c & 15;
      const unsigned short* gs = A16 + (size_t)(m0 + row) * K + k0 +
                                 ((kc ^ (row & 15)) << 3);
      __builtin_amdgcn_global_load_lds(
          (const __attribute__((address_space(1))) u32*)gs,
          (__attribute__((address_space(3))) u32*)&As8[c], 16, 0, 0);
    }
    #pragma unroll
    for (int i = 0; i < (BN * 16) / 512; ++i) {
      const int c = tid + i * 512;
      const int row = c >> 4, kc = c & 15;
      const unsigned short* gs = W16 + (size_t)(n0 + row) * K + k0 +
                                 ((kc ^ (row & 15)) << 3);
      __builtin_amdgcn_global_load_lds(
          (const __attribute__((address_space(1))) u32*)gs,
          (__attribute__((address_space(3))) u32*)&Bs8[c], 16, 0, 0);
    }
    asm volatile("s_waitcnt vmcnt(0)" ::: "memory");
    __builtin_amdgcn_sched_barrier(0);
    __builtin_amdgcn_s_barrier();

    __builtin_amdgcn_s_setprio(1);
    #pragma unroll
    for (int s = 0; s < 4; ++s) {
      short8 af[4], bf[2];
      #pragma unroll
      for (int m = 0; m < 4; ++m) {
        const int r2 = wr * 64 + m * 16 + lrc;
        af[m] = As8[r2 * 16 + ((s * 4 + lkc) ^ (r2 & 15))];
      }
      #pragma unroll
      for (int n = 0; n < 2; ++n) {
        const int cn = wc * 32 + n * 16 + lrc;
        bf[n] = Bs8[cn * 16 + ((s * 4 + lkc) ^ (cn & 15))];
      }
      #pragma unroll
      for (int m = 0; m < 4; ++m)
        #pragma unroll
        for (int n = 0; n < 2; ++n)
          acc[m][n] = __builtin_amdgcn_mfma_f32_16x16x32_bf16(
              af[m], bf[n], acc[m][n], 0, 0, 0);
    }
    __builtin_amdgcn_s_setprio(0);
  }

  // ---- direct epilogue ----
  const int r0 = lkc * 4;
  #pragma unroll
  for (int m = 0; m < 4; ++m) {
    const int gmb = m0 + wr * 64 + m * 16 + r0;
    #pragma unroll
    for (int n = 0; n < 2; ++n) {
      const int gn = n0 + wc * 32 + n * 16 + lrc;
      const float bb = BIAS ? bias[gn] : 0.f;
      #pragma unroll
      for (int j = 0; j < 4; ++j) {
        float v = acc[m][n][j] + bb;
        if (RELU) v = fmaxf(v, 0.f);
        if (CBF16) C16[(size_t)(gmb + j) * N + gn] = f2b(v);
        else       Cf[(size_t)(gmb + j) * N + gn] = v;
      }
    }
  }
}

// ---------------------------------------------------------------------------
// Conv compression, K and V in one dispatch (blockIdx.z): z=0 reads g_tb
// (k proj) -> g_kc with null_k edge; z=1 reads g_ffh (v proj) -> g_vc.
__global__ __launch_bounds__(256) void compress2_k(
    const float* __restrict__ cw, const float* __restrict__ cb,
    const float* __restrict__ nk, const float* __restrict__ nv) {
  __shared__ float rows[32][256];       // 32 KB
  const int tc0 = 1 + blockIdx.x * 16;
  const int b = blockIdx.y;
  const int z = blockIdx.z;
  const int tid = threadIdx.x;
  const int o = tid;
  const int g = o >> 5;

  const unsigned short* srcbuf = z ? g_ffh : g_tb;
  const float* nul = z ? nv : nk;
  float* outb = (z ? g_vc : g_kc) + (size_t)b * Tkv * Dm;

  const int r0g = 2 * tc0 - 2;
  const unsigned short* src = srcbuf + ((size_t)b * Tt + r0g) * Dm;
  #pragma unroll
  for (int i = 0; i < 4; ++i) {
    const int c = tid + i * 256;        // 1024 chunks of 8
    const int row = c >> 5, off = (c & 31) * 8;
    short8 v = *(const short8*)(src + (size_t)row * 256 + off);
    #pragma unroll
    for (int j = 0; j < 8; ++j)
      rows[row][off + j] = b2f((unsigned short)v[j]);
  }

  float we[32], wo[32];
  {
    const float4* wp = (const float4*)(cw + o * 64);
    #pragma unroll
    for (int i = 0; i < 16; ++i) {
      float4 w4 = wp[i];
      we[i * 2 + 0] = w4.x; wo[i * 2 + 0] = w4.y;
      we[i * 2 + 1] = w4.z; wo[i * 2 + 1] = w4.w;
    }
  }
  const float bias = cb[o];
  if (blockIdx.x == 0) {                // edge rows j=0,1
    outb[o] = nul[b * Dm + o];
    outb[Dm + o] = bias;
  }
  __syncthreads();

  float* outp = outb + o;
  #pragma unroll
  for (int t = 0; t < 16; ++t) {
    const int lr = 2 * t;
    const float* p0 = &rows[lr][g * 32];
    const float* p1 = &rows[lr + 1][g * 32];
    float acc = bias;
    #pragma unroll
    for (int i4 = 0; i4 < 8; ++i4) {
      float4 a0 = *(const float4*)(p0 + i4 * 4);
      float4 a1 = *(const float4*)(p1 + i4 * 4);
      acc = fmaf(we[i4 * 4 + 0], a0.x, acc);
      acc = fmaf(we[i4 * 4 + 1], a0.y, acc);
      acc = fmaf(we[i4 * 4 + 2], a0.z, acc);
      acc = fmaf(we[i4 * 4 + 3], a0.w, acc);
      acc = fmaf(wo[i4 * 4 + 0], a1.x, acc);
      acc = fmaf(wo[i4 * 4 + 1], a1.y, acc);
      acc = fmaf(wo[i4 * 4 + 2], a1.z, acc);
      acc = fmaf(wo[i4 * 4 + 3], a1.w, acc);
    }
    outp[(size_t)(1 + tc0 + t) * Dm] = acc;
  }
}

// ---------------------------------------------------------------------------
// KV reduction stage 1/2 (validated).
__global__ __launch_bounds__(256) void kvout1_k() {
  __shared__ float kl[8][32];
  __shared__ float vl[8][32];
  const int bh = blockIdx.x;
  const int js = blockIdx.y;
  const int b = bh >> 3, h = bh & 7;
  const int j0 = js * 101;
  const int jend = (j0 + 101 < Tkv) ? j0 + 101 : Tkv;

  const int tid = threadIdx.x;
  const int lr = tid >> 5;
  const int lc = tid & 31;
  const int e = tid >> 3;
  const int d0 = (tid & 7) * 4;

  float a0 = 0.f, a1 = 0.f, a2 = 0.f, a3 = 0.f;
  const size_t base = (size_t)b * Tkv * Dm + h * 32;

  for (int jc = j0; jc < jend; jc += 8) {
    const int jr = jc + lr;
    if (jr < jend) {
      kl[lr][lc] = g_kc[base + (size_t)jr * Dm + lc];
      vl[lr][lc] = g_vc[base + (size_t)jr * Dm + lc];
    } else {
      kl[lr][lc] = 0.f;
      vl[lr][lc] = 0.f;
    }
    __syncthreads();
    #pragma unroll
    for (int r = 0; r < 8; ++r) {
      const float kf = kl[r][e];
      const float* vr = &vl[r][d0];
      a0 = fmaf(kf, vr[0], a0);
      a1 = fmaf(kf, vr[1], a1);
      a2 = fmaf(kf, vr[2], a2);
      a3 = fmaf(kf, vr[3], a3);
    }
    __syncthreads();
  }
  float* op = g_kvp + ((size_t)js * 80 + bh) * 1024 + e * 32 + d0;
  op[0] = a0; op[1] = a1; op[2] = a2; op[3] = a3;
}

__global__ __launch_bounds__(256) void kvout2_k() {
  const int bh = blockIdx.x;
  const int tid = threadIdx.x;
  const int e = tid >> 3;
  const int d0 = (tid & 7) * 4;
  float a0 = 0.f, a1 = 0.f, a2 = 0.f, a3 = 0.f;
  #pragma unroll
  for (int s = 0; s < JCH; ++s) {
    const float* p = g_kvp + ((size_t)s * 80 + bh) * 1024 + e * 32 + d0;
    a0 += p[0]; a1 += p[1]; a2 += p[2]; a3 += p[3];
  }
  float* op = g_kvm + (size_t)bh * 1024 + e * 32 + d0;
  op[0] = a0 * 0.0625f;
  op[1] = a1 * 0.0625f;
  op[2] = a2 * 0.0625f;
  op[3] = a3 * 0.0625f;
}

// ---------------------------------------------------------------------------
// W'[b,n,h*32+e] = sum_d kvm[b,h,e,d] * Wo[n,h*32+d]   (bf16 out)
__global__ __launch_bounds__(256) void wo2_k(int wooff) {
  const int n = blockIdx.x, b = blockIdx.y;
  const int he = threadIdx.x;
  const int h = he >> 5, e = he & 31;
  const float* kp = g_kvm + ((size_t)(b * Hh + h) * 32 + e) * 32;
  const unsigned short* wp = g_wb + wooff + (size_t)n * Dm + h * 32;
  float acc = 0.f;
  #pragma unroll
  for (int d = 0; d < 32; ++d) acc = fmaf(kp[d], b2f(wp[d]), acc);
  g_wo2[(size_t)b * 65536 + (size_t)n * Dm + he] = f2b(acc);
}

// ---------------------------------------------------------------------------
// x = LN(x + d1 [+ d2])*g + beta (fp32), writes bf16 shadow g_xb.
// If do_pos: also writes g_qkb = bf16(ln_out + pos).
__global__ __launch_bounds__(256) void ln_k(int did, int did2, const float* g,
                                            const float* beta, int do_pos) {
  const int lane = threadIdx.x & 63;
  const int wave = threadIdx.x >> 6;
  const size_t row = (size_t)blockIdx.x * 4 + wave;
  float4 xv = ((const float4*)g_x)[row * 64 + lane];
  float4 dv = ((const float4*)selbuf(did))[row * 64 + lane];
  float v[4] = {xv.x + dv.x, xv.y + dv.y, xv.z + dv.z, xv.w + dv.w};
  if (did2 >= 0) {
    float4 d2 = ((const float4*)selbuf(did2))[row * 64 + lane];
    v[0] += d2.x; v[1] += d2.y; v[2] += d2.z; v[3] += d2.w;
  }
  float sum = v[0] + v[1] + v[2] + v[3];
  float sq = v[0]*v[0] + v[1]*v[1] + v[2]*v[2] + v[3]*v[3];
  #pragma unroll
  for (int off = 32; off; off >>= 1) {
    sum += __shfl_xor(sum, off);
    sq  += __shfl_xor(sq, off);
  }
  const float mean = sum * (1.f / 256.f);
  const float var = sq * (1.f / 256.f) - mean * mean;
  const float rs = rsqrtf(var + 1e-5f);
  float4 gg = ((const float4*)g)[lane];
  float4 bb = ((const float4*)beta)[lane];
  float4 ov;
  ov.x = (v[0] - mean) * rs * gg.x + bb.x;
  ov.y = (v[1] - mean) * rs * gg.y + bb.y;
  ov.z = (v[2] - mean) * rs * gg.z + bb.z;
  ov.w = (v[3] - mean) * rs * gg.w + bb.w;
  ((float4*)g_x)[row * 64 + lane] = ov;
  short4v sv;
  sv[0] = (short)f2b(ov.x); sv[1] = (short)f2b(ov.y);
  sv[2] = (short)f2b(ov.z); sv[3] = (short)f2b(ov.w);
  *(short4v*)&g_xb[(row * 64 + lane) * 4] = sv;
  if (do_pos) {
    float4 pv = ((const float4*)g_pos)[row * 64 + lane];
    short4v qv;
    qv[0] = (short)f2b(ov.x + pv.x); qv[1] = (short)f2b(ov.y + pv.y);
    qv[2] = (short)f2b(ov.z + pv.z); qv[3] = (short)f2b(ov.w + pv.w);
    *(short4v*)&g_qkb[(row * 64 + lane) * 4] = qv;
  }
}

// ---------------------------------------------------------------------------
extern "C" void kernel_launch(void* const* d_in, const int* in_sizes, int n_in,
                              void* d_out, int out_size, void* d_ws, size_t ws_size,
                              hipStream_t stream) {
  const float* src  = (const float*)d_in[0];
  const float* pose = (const float*)d_in[1];
  const float* Wq   = (const float*)d_in[2];
  const float* Wk   = (const float*)d_in[3];
  const float* Wv   = (const float*)d_in[4];
  const float* Wo   = (const float*)d_in[5];
  const float* bo   = (const float*)d_in[6];
  const float* cw   = (const float*)d_in[7];
  const float* cb   = (const float*)d_in[8];
  const float* nk   = (const float*)d_in[9];
  const float* nv   = (const float*)d_in[10];
  const float* ln1g = (const float*)d_in[11];
  const float* ln1b = (const float*)d_in[12];
  const float* ln2g = (const float*)d_in[13];
  const float* ln2b = (const float*)d_in[14];
  const float* W1   = (const float*)d_in[15];
  const float* b1   = (const float*)d_in[16];
  const float* W2   = (const float*)d_in[17];
  const float* b2   = (const float*)d_in[18];

  const int MT = Bsz * Tt;        // 16000
  const dim3 tgrid(Tt / 32, Dm / 32, Bsz);

  // g_wb layout: per-layer [Wk|Wq] at l*131072; then Wv, Wo, W1, W2.
  const int OV = 262144, OO = 393216, O1 = 524288, O2 = 1572864;
  wconv_all_k<<<10240, 256, 0, stream>>>(Wk, Wq, Wv, Wo, W1, W2);
  trans_in2_k<<<tgrid, 256, 0, stream>>>(src, pose);  // x, xb, pos, qkb

  const int MB = MT / 128;  // 125 m-blocks
  for (int l = 0; l < 2; ++l) {
    const float* bo_l = bo + (size_t)l * Dm;
    const float* cw_l = cw + (size_t)l * Dm * 64;
    const float* cb_l = cb + (size_t)l * Dm;
    const float* nk_l = nk + (size_t)l * Bsz * Dm;
    const float* nv_l = nv + (size_t)l * Bsz * Dm;
    const float* b1_l = b1 + (size_t)l * FFd;
    const float* b2_l = b2 + (size_t)l * Dm;
    const int wkq = l * 131072;
    const int wv = OV + l * 65536, wo = OO + l * 65536;
    const int w1 = O1 + l * 524288, w2 = O2 + l * 524288;

    // [k|q] = qkb @ [Wk|Wq]^T : k -> tb, q -> qb (N=512 dual-dest, NB=8)
    gemm2_k<64, true, false, false, false, true><<<8 * MB, 256, 0, stream>>>(
        1, wkq, nullptr, 2, 4, 8, MT, 512, Dm);
    // v = xb @ Wv^T -> ffh (free until FF1)  (NB=4)
    gemm2_k<64, false, false, false, false, true><<<4 * MB, 256, 0, stream>>>(
        0, wv, nullptr, 3, 3, 4, MT, Dm, Dm);
    // compress K (tb->kc) and V (ffh->vc) in one dispatch
    compress2_k<<<dim3(50, Bsz, 2), 256, 0, stream>>>(cw_l, cb_l, nk_l, nv_l);
    // kvm = (1/16) kc^T vc
    kvout1_k<<<dim3(Bsz * Hh, JCH), 256, 0, stream>>>();
    kvout2_k<<<Bsz * Hh, 256, 0, stream>>>();
    // W' = kvm (×) Wo  (per-b fused attn+Wo weights)
    wo2_k<<<dim3(Dm, Bsz), 256, 0, stream>>>(wo);
    // t = qb @ W'^T + bo (fp32, per-b) ; x = LN(x + t)
    gemm2_k<64, false, true, false, true, false><<<Bsz * 13 * 4, 256, 0, stream>>>(
        4, 0, bo_l, 2, 2, 4, MT, Dm, Dm);
    ln_k<<<MT / 4, 256, 0, stream>>>(2, -1, ln1g + l * Dm, ln1b + l * Dm, 0);

    // FF1: ffh = bf16(relu(xb @ W1^T + b1))  [K-halved, 64KB LDS, grid 2000]
    gemmh_k<true, true, true><<<16 * MB, 512, 0, stream>>>(
        0, w1, b1_l, 3, 16, MT, FFd);
    // FF2: N-resident K-split: half0 -> g_qk (+b2), half1 -> g_t  [grid 250]
    gemmn_k<<<2 * MB, 512, 0, stream>>>(3, w2, b2_l, FFd);
    // LN2 sums both FF2 halves; layer 0 fused with next layer's pos-add.
    ln_k<<<MT / 4, 256, 0, stream>>>(1, 2, ln2g + l * Dm, ln2b + l * Dm,
                                     l == 0 ? 1 : 0);
  }

  trans_out_k<<<tgrid, 256, 0, stream>>>((float*)d_out);
}

// Round 4
// 368.610 us; speedup vs baseline: 1.2283x; 1.0450x over previous
//
#include <hip/hip_runtime.h>
#include <math.h>

typedef __attribute__((ext_vector_type(8))) short short8;   // 8 bf16
typedef __attribute__((ext_vector_type(4))) short short4v;  // 4 bf16
typedef __attribute__((ext_vector_type(4))) float f32x4;
typedef unsigned int u32;

constexpr int Bsz = 10;
constexpr int Dm  = 256;
constexpr int Hh  = 8;
constexpr int Tt  = 1600;
constexpr int FFd = 2048;
constexpr int Tkv = 802;   // 1 null + 801 compressed
constexpr int JCH = 8;     // j-splits for kv reduction
constexpr size_t Fsz  = (size_t)Bsz * Tt * Dm;    // 4,096,000
constexpr size_t PAD  = 65536;
constexpr size_t KVsz = (size_t)Bsz * Tkv * Dm;   // 2,053,120
constexpr size_t FHsz = (size_t)Bsz * Tt * FFd;   // 32,768,000
constexpr size_t WBsz = 2621440;                  // all weights, bf16

// Static device scratch; referenced ONLY from device code.
__device__ float g_x[Fsz];                        // residual stream fp32
__device__ float g_qk[Fsz];                       // FF2 out (LN2 delta)
__device__ float g_t[Fsz];                        // Wo out (LN1 delta)
__device__ float g_kc[KVsz];                      // compressed K
__device__ float g_vc[KVsz];                      // compressed V
__device__ float g_kvm[(size_t)Bsz * Hh * 32 * 32];
__device__ float g_kvp[(size_t)JCH * Bsz * Hh * 32 * 32];
__device__ float g_pos[Fsz];                      // transposed pos fp32
__device__ unsigned short g_xb[Fsz + PAD];        // bf16 shadow of x
__device__ unsigned short g_qkb[Fsz + PAD];       // bf16 x+pos
__device__ unsigned short g_tb[Fsz + PAD];        // bf16 k projection
__device__ unsigned short g_qb[Fsz + PAD];        // bf16 q projection
__device__ unsigned short g_ffh[FHsz + PAD];      // bf16 FF hidden / v proj
__device__ unsigned short g_wb[WBsz];             // bf16 weights
__device__ unsigned short g_wo2[(size_t)Bsz * Dm * Dm];  // per-b fused kvm*Wo

__device__ __forceinline__ float* selbuf(int id) {
  switch (id) {
    case 0: return g_x;
    case 1: return g_qk;
    case 2: return g_t;
    case 3: return g_kc;
    case 4: return g_vc;
    default: return g_kvm;
  }
}
__device__ __forceinline__ unsigned short* selbufb(int id) {
  switch (id) {
    case 0: return g_xb;
    case 1: return g_qkb;
    case 2: return g_tb;
    case 3: return g_ffh;
    default: return g_qb;
  }
}

// fp32 -> bf16 (RNE)
__device__ __forceinline__ unsigned short f2b(float x) {
  unsigned int u = __float_as_uint(x);
  u += 0x7FFFu + ((u >> 16) & 1u);
  return (unsigned short)(u >> 16);
}
__device__ __forceinline__ float b2f(unsigned short u) {
  return __uint_as_float(((unsigned int)u) << 16);
}

// ---------------------------------------------------------------------------
// ALL weight conversions in one dispatch. g_wb layout:
// [l0:Wk|Wq][l1:Wk|Wq] | Wv(l0,l1) | Wo(l0,l1) | W1(l0,l1) | W2(l0,l1)
__global__ __launch_bounds__(256) void wconv_all_k(
    const float* __restrict__ Wk, const float* __restrict__ Wq,
    const float* __restrict__ Wv, const float* __restrict__ Wo,
    const float* __restrict__ W1, const float* __restrict__ W2) {
  const int i = blockIdx.x * 256 + threadIdx.x;   // < 2,621,440
  float v;
  if (i < 262144) {
    const int l = i >> 17, r = i & 131071;
    v = (r < 65536) ? Wk[l * 65536 + r] : Wq[l * 65536 + (r - 65536)];
  } else if (i < 393216) {
    v = Wv[i - 262144];
  } else if (i < 524288) {
    v = Wo[i - 393216];
  } else if (i < 1572864) {
    v = W1[i - 524288];
  } else {
    v = W2[i - 1572864];
  }
  g_wb[i] = f2b(v);
}

// ---------------------------------------------------------------------------
// Fused input transpose + pos-add: src,pose [B,D,T] -> g_x, g_xb, g_pos,
// g_qkb = bf16(x+pos).
__global__ __launch_bounds__(256) void trans_in2_k(const float* __restrict__ src,
                                                   const float* __restrict__ pose) {
  __shared__ float ts[32][33];
  __shared__ float tp[32][33];
  const int tx = threadIdx.x & 31, ty = threadIdx.x >> 5;
  const int t0 = blockIdx.x * 32, d0 = blockIdx.y * 32, b = blockIdx.z;
  #pragma unroll
  for (int i = ty; i < 32; i += 8) {
    const size_t gi = ((size_t)(b * Dm + d0 + i)) * Tt + t0 + tx;
    ts[i][tx] = src[gi];
    tp[i][tx] = pose[gi];
  }
  __syncthreads();
  #pragma unroll
  for (int i = ty; i < 32; i += 8) {
    const size_t idx = ((size_t)(b * Tt + t0 + i)) * Dm + d0 + tx;
    const float s = ts[tx][i], p = tp[tx][i];
    g_x[idx] = s;
    g_pos[idx] = p;
    g_xb[idx] = f2b(s);
    g_qkb[idx] = f2b(s + p);
  }
}

__global__ __launch_bounds__(256) void trans_out_k(float* out) {
  __shared__ float tile[32][33];
  const int tx = threadIdx.x & 31, ty = threadIdx.x >> 5;
  const int t0 = blockIdx.x * 32, d0 = blockIdx.y * 32, b = blockIdx.z;
  #pragma unroll
  for (int i = ty; i < 32; i += 8)
    tile[i][tx] = g_x[((size_t)(b * Tt + t0 + i)) * Dm + d0 + tx];
  __syncthreads();
  #pragma unroll
  for (int i = ty; i < 32; i += 8)
    out[((size_t)(b * Dm + d0 + i)) * Tt + t0 + tx] = tile[tx][i];
}

// ---------------------------------------------------------------------------
// MFMA GEMM: C[M,N] = A[M,K](bf16) @ W[N,K](bf16)^T (+bias)(+relu).
// BM=128, BN=64, BK=64; 4 waves (2x2). 1-D grid + bijective XCD swizzle.
// PIPELINE (round-4): 3 LDS buffers, ONE barrier per K-step, stage hoisted
// BEFORE compute. Invariant: after barrier(t) all waves finished
// compute(t-1), so buf[(t+2)%3] == buf[(t-1)%3] is free to overwrite.
// Loads get ~2 compute phases to land (vs 1 barrier-gap in the 2-buf/2-bar
// version); one fewer barrier drain per step. LDS 72KB -> 2 blocks/CU.
// DUAL (N=512 merged KQ): n0<256 -> Cid, n0>=256 -> C2id, stride 256.
// PERB: per-batch weights g_wo2 (13 m-blocks x NB per b), guarded stores.
template<int BN, bool DUAL, bool PERB, bool RELU, bool BIAS, bool CBF16>
__global__ __launch_bounds__(256) void gemm2_k(
    int Aid, int woff, const float* __restrict__ bias, int Cid, int C2id,
    int NB, int M, int N, int K) {
  constexpr int BM = 128, BK = 64;
  constexpr int ACH = BM * 8;           // 1024 short8 (16 KB)
  constexpr int BCH = BN * 8;           // 512 short8 (8 KB) for BN=64
  constexpr int NW = BN / 32;           // n-frags per wave: 2 or 4
  __shared__ short8 As8[3][ACH];
  __shared__ short8 Bs8[3][BCH];
  const int tid = threadIdx.x;
  const int lane = tid & 63, wid = tid >> 6;
  const int wr = wid >> 1, wc = wid & 1;

  // XCD-aware bijective remap (m204).
  const int nwg = gridDim.x;
  const int bid = blockIdx.x;
  const int q = nwg >> 3, r = nwg & 7;
  const int xcd = bid & 7, seq = bid >> 3;
  const int wgid = (xcd < r ? xcd * (q + 1) : r * (q + 1) + (xcd - r) * q) + seq;

  int m0, n0, mlim;
  const unsigned short* W16;
  if constexpr (PERB) {
    const int per = 13 * NB;
    const int b = wgid / per;
    const int rem = wgid - b * per;
    m0 = b * Tt + (rem / NB) * BM;
    n0 = (rem % NB) * BN;
    mlim = b * Tt + Tt;
    W16 = g_wo2 + (size_t)b * 65536;
  } else {
    m0 = (wgid / NB) * BM;
    n0 = (wgid % NB) * BN;
    mlim = M;
    W16 = g_wb + woff;
  }

  const unsigned short* A16 = selbufb(Aid);
  const bool second = DUAL && (n0 >= 256);
  float* Cf = selbuf(second ? C2id : Cid);
  unsigned short* C16 = selbufb(second ? C2id : Cid);
  const int gn0 = second ? n0 - 256 : n0;
  const int cstride = DUAL ? 256 : N;

  f32x4 acc[4][NW];
  #pragma unroll
  for (int m = 0; m < 4; ++m)
    #pragma unroll
    for (int n = 0; n < NW; ++n) acc[m][n] = (f32x4){0.f, 0.f, 0.f, 0.f};

  const int lkc = lane >> 4, lrc = lane & 15;

  auto stage = [&](int t, int buf) {
    const int k0 = t * BK;
    #pragma unroll
    for (int i = 0; i < ACH / 256; ++i) {
      const int c = tid + i * 256;
      const int row = c >> 3, kc = c & 7;
      const unsigned short* gs = A16 + (size_t)(m0 + row) * K + k0 +
                                 ((kc ^ (row & 7)) << 3);
      __builtin_amdgcn_global_load_lds(
          (const __attribute__((address_space(1))) u32*)gs,
          (__attribute__((address_space(3))) u32*)&As8[buf][c], 16, 0, 0);
    }
    #pragma unroll
    for (int i = 0; i < BCH / 256; ++i) {
      const int c = tid + i * 256;
      const int row = c >> 3, kc = c & 7;
      const unsigned short* gs = W16 + (size_t)(n0 + row) * K + k0 +
                                 ((kc ^ (row & 7)) << 3);
      __builtin_amdgcn_global_load_lds(
          (const __attribute__((address_space(1))) u32*)gs,
          (__attribute__((address_space(3))) u32*)&Bs8[buf][c], 16, 0, 0);
    }
  };

  const int nt = K / BK;
  stage(0, 0);
  if (nt > 1) stage(1, 1);
  int cur = 0, nxt = 2;                 // nxt = (t+2)%3 target
  for (int t = 0; t < nt; ++t) {
    if (t + 1 < nt) {
      if constexpr (BN == 64)
        asm volatile("s_waitcnt vmcnt(6)" ::: "memory");
      else
        asm volatile("s_waitcnt vmcnt(8)" ::: "memory");
    } else {
      asm volatile("s_waitcnt vmcnt(0)" ::: "memory");
    }
    __builtin_amdgcn_sched_barrier(0);
    __builtin_amdgcn_s_barrier();       // buf[cur] landed for ALL waves;
                                        // ALL waves done reading buf[nxt]
    __builtin_amdgcn_sched_barrier(0);
    if (t + 2 < nt) stage(t + 2, nxt);  // overlaps with compute below
    #pragma unroll
    for (int kk = 0; kk < 2; ++kk) {
      short8 af[4], bf[NW];
      #pragma unroll
      for (int m = 0; m < 4; ++m) {
        const int r2 = wr * 64 + m * 16 + lrc;
        af[m] = As8[cur][r2 * 8 + ((kk * 4 + lkc) ^ (r2 & 7))];
      }
      #pragma unroll
      for (int n = 0; n < NW; ++n) {
        const int cn = wc * (BN / 2) + n * 16 + lrc;
        bf[n] = Bs8[cur][cn * 8 + ((kk * 4 + lkc) ^ (cn & 7))];
      }
      #pragma unroll
      for (int m = 0; m < 4; ++m)
        #pragma unroll
        for (int n = 0; n < NW; ++n)
          acc[m][n] = __builtin_amdgcn_mfma_f32_16x16x32_bf16(
              af[m], bf[n], acc[m][n], 0, 0, 0);
    }
    cur = (cur == 2) ? 0 : cur + 1;
    nxt = (nxt == 2) ? 0 : nxt + 1;
  }

  // ---- LDS-staged epilogue: deposit acc, then coalesced row stores ----
  constexpr int CSTR = (BN == 64) ? BN + 4 : BN;
  float* ldsC = (float*)&As8[0][0];
  {
    asm volatile("s_waitcnt vmcnt(0)" ::: "memory");
    __builtin_amdgcn_s_barrier();       // all waves done reading As8/Bs8
    const int r0 = lkc * 4;
    #pragma unroll
    for (int m = 0; m < 4; ++m)
      #pragma unroll
      for (int n = 0; n < NW; ++n) {
        const int col = wc * (BN / 2) + n * 16 + lrc;
        #pragma unroll
        for (int j = 0; j < 4; ++j)
          ldsC[(wr * 64 + m * 16 + r0 + j) * CSTR + col] = acc[m][n][j];
      }
    __syncthreads();
  }
  if constexpr (CBF16) {
    constexpr int CH = BM * BN / 8;     // short8 chunks
    #pragma unroll
    for (int i = 0; i < CH / 256; ++i) {
      const int c = tid + i * 256;
      const int rowl = c / (BN / 8), col8 = (c % (BN / 8)) * 8;
      if (PERB && m0 + rowl >= mlim) continue;
      short8 v;
      #pragma unroll
      for (int j = 0; j < 8; ++j) {
        float x = ldsC[rowl * CSTR + col8 + j];
        if (BIAS) x += bias[gn0 + col8 + j];
        if (RELU) x = fmaxf(x, 0.f);
        v[j] = (short)f2b(x);
      }
      *(short8*)(C16 + (size_t)(m0 + rowl) * cstride + gn0 + col8) = v;
    }
  } else {
    constexpr int CH = BM * BN / 4;     // float4 chunks
    #pragma unroll
    for (int i = 0; i < CH / 256; ++i) {
      const int c = tid + i * 256;
      const int rowl = c / (BN / 4), col4 = (c % (BN / 4)) * 4;
      if (PERB && m0 + rowl >= mlim) continue;
      float4 v;
      float* pv = &v.x;
      #pragma unroll
      for (int j = 0; j < 4; ++j) {
        float x = ldsC[rowl * CSTR + col4 + j];
        if (BIAS) x += bias[gn0 + col4 + j];
        if (RELU) x = fmaxf(x, 0.f);
        pv[j] = x;
      }
      *(float4*)(Cf + (size_t)(m0 + rowl) * cstride + gn0 + col4) = v;
    }
  }
}

// ---------------------------------------------------------------------------
// Conv compression, K and V in one dispatch (blockIdx.z): z=0 reads g_tb
// (k proj) -> g_kc with null_k edge; z=1 reads g_ffh (v proj) -> g_vc.
__global__ __launch_bounds__(256) void compress2_k(
    const float* __restrict__ cw, const float* __restrict__ cb,
    const float* __restrict__ nk, const float* __restrict__ nv) {
  __shared__ float rows[32][256];       // 32 KB
  const int tc0 = 1 + blockIdx.x * 16;
  const int b = blockIdx.y;
  const int z = blockIdx.z;
  const int tid = threadIdx.x;
  const int o = tid;
  const int g = o >> 5;

  const unsigned short* srcbuf = z ? g_ffh : g_tb;
  const float* nul = z ? nv : nk;
  float* outb = (z ? g_vc : g_kc) + (size_t)b * Tkv * Dm;

  const int r0g = 2 * tc0 - 2;
  const unsigned short* src = srcbuf + ((size_t)b * Tt + r0g) * Dm;
  #pragma unroll
  for (int i = 0; i < 4; ++i) {
    const int c = tid + i * 256;        // 1024 chunks of 8
    const int row = c >> 5, off = (c & 31) * 8;
    short8 v = *(const short8*)(src + (size_t)row * 256 + off);
    #pragma unroll
    for (int j = 0; j < 8; ++j)
      rows[row][off + j] = b2f((unsigned short)v[j]);
  }

  float we[32], wo[32];
  {
    const float4* wp = (const float4*)(cw + o * 64);
    #pragma unroll
    for (int i = 0; i < 16; ++i) {
      float4 w4 = wp[i];
      we[i * 2 + 0] = w4.x; wo[i * 2 + 0] = w4.y;
      we[i * 2 + 1] = w4.z; wo[i * 2 + 1] = w4.w;
    }
  }
  const float bias = cb[o];
  if (blockIdx.x == 0) {                // edge rows j=0,1
    outb[o] = nul[b * Dm + o];
    outb[Dm + o] = bias;
  }
  __syncthreads();

  float* outp = outb + o;
  #pragma unroll
  for (int t = 0; t < 16; ++t) {
    const int lr = 2 * t;
    const float* p0 = &rows[lr][g * 32];
    const float* p1 = &rows[lr + 1][g * 32];
    float acc = bias;
    #pragma unroll
    for (int i4 = 0; i4 < 8; ++i4) {
      float4 a0 = *(const float4*)(p0 + i4 * 4);
      float4 a1 = *(const float4*)(p1 + i4 * 4);
      acc = fmaf(we[i4 * 4 + 0], a0.x, acc);
      acc = fmaf(we[i4 * 4 + 1], a0.y, acc);
      acc = fmaf(we[i4 * 4 + 2], a0.z, acc);
      acc = fmaf(we[i4 * 4 + 3], a0.w, acc);
      acc = fmaf(wo[i4 * 4 + 0], a1.x, acc);
      acc = fmaf(wo[i4 * 4 + 1], a1.y, acc);
      acc = fmaf(wo[i4 * 4 + 2], a1.z, acc);
      acc = fmaf(wo[i4 * 4 + 3], a1.w, acc);
    }
    outp[(size_t)(1 + tc0 + t) * Dm] = acc;
  }
}

// ---------------------------------------------------------------------------
// KV reduction stage 1/2 (validated).
__global__ __launch_bounds__(256) void kvout1_k() {
  __shared__ float kl[8][32];
  __shared__ float vl[8][32];
  const int bh = blockIdx.x;
  const int js = blockIdx.y;
  const int b = bh >> 3, h = bh & 7;
  const int j0 = js * 101;
  const int jend = (j0 + 101 < Tkv) ? j0 + 101 : Tkv;

  const int tid = threadIdx.x;
  const int lr = tid >> 5;
  const int lc = tid & 31;
  const int e = tid >> 3;
  const int d0 = (tid & 7) * 4;

  float a0 = 0.f, a1 = 0.f, a2 = 0.f, a3 = 0.f;
  const size_t base = (size_t)b * Tkv * Dm + h * 32;

  for (int jc = j0; jc < jend; jc += 8) {
    const int jr = jc + lr;
    if (jr < jend) {
      kl[lr][lc] = g_kc[base + (size_t)jr * Dm + lc];
      vl[lr][lc] = g_vc[base + (size_t)jr * Dm + lc];
    } else {
      kl[lr][lc] = 0.f;
      vl[lr][lc] = 0.f;
    }
    __syncthreads();
    #pragma unroll
    for (int r = 0; r < 8; ++r) {
      const float kf = kl[r][e];
      const float* vr = &vl[r][d0];
      a0 = fmaf(kf, vr[0], a0);
      a1 = fmaf(kf, vr[1], a1);
      a2 = fmaf(kf, vr[2], a2);
      a3 = fmaf(kf, vr[3], a3);
    }
    __syncthreads();
  }
  float* op = g_kvp + ((size_t)js * 80 + bh) * 1024 + e * 32 + d0;
  op[0] = a0; op[1] = a1; op[2] = a2; op[3] = a3;
}

__global__ __launch_bounds__(256) void kvout2_k() {
  const int bh = blockIdx.x;
  const int tid = threadIdx.x;
  const int e = tid >> 3;
  const int d0 = (tid & 7) * 4;
  float a0 = 0.f, a1 = 0.f, a2 = 0.f, a3 = 0.f;
  #pragma unroll
  for (int s = 0; s < JCH; ++s) {
    const float* p = g_kvp + ((size_t)s * 80 + bh) * 1024 + e * 32 + d0;
    a0 += p[0]; a1 += p[1]; a2 += p[2]; a3 += p[3];
  }
  float* op = g_kvm + (size_t)bh * 1024 + e * 32 + d0;
  op[0] = a0 * 0.0625f;
  op[1] = a1 * 0.0625f;
  op[2] = a2 * 0.0625f;
  op[3] = a3 * 0.0625f;
}

// ---------------------------------------------------------------------------
// W'[b,n,h*32+e] = sum_d kvm[b,h,e,d] * Wo[n,h*32+d]   (bf16 out)
__global__ __launch_bounds__(256) void wo2_k(int wooff) {
  const int n = blockIdx.x, b = blockIdx.y;
  const int he = threadIdx.x;
  const int h = he >> 5, e = he & 31;
  const float* kp = g_kvm + ((size_t)(b * Hh + h) * 32 + e) * 32;
  const unsigned short* wp = g_wb + wooff + (size_t)n * Dm + h * 32;
  float acc = 0.f;
  #pragma unroll
  for (int d = 0; d < 32; ++d) acc = fmaf(kp[d], b2f(wp[d]), acc);
  g_wo2[(size_t)b * 65536 + (size_t)n * Dm + he] = f2b(acc);
}

// ---------------------------------------------------------------------------
// x = LN(x + d1 [+ d2])*g + beta (fp32), writes bf16 shadow g_xb.
// If do_pos: also writes g_qkb = bf16(ln_out + pos).
__global__ __launch_bounds__(256) void ln_k(int did, int did2, const float* g,
                                            const float* beta, int do_pos) {
  const int lane = threadIdx.x & 63;
  const int wave = threadIdx.x >> 6;
  const size_t row = (size_t)blockIdx.x * 4 + wave;
  float4 xv = ((const float4*)g_x)[row * 64 + lane];
  float4 dv = ((const float4*)selbuf(did))[row * 64 + lane];
  float v[4] = {xv.x + dv.x, xv.y + dv.y, xv.z + dv.z, xv.w + dv.w};
  if (did2 >= 0) {
    float4 d2 = ((const float4*)selbuf(did2))[row * 64 + lane];
    v[0] += d2.x; v[1] += d2.y; v[2] += d2.z; v[3] += d2.w;
  }
  float sum = v[0] + v[1] + v[2] + v[3];
  float sq = v[0]*v[0] + v[1]*v[1] + v[2]*v[2] + v[3]*v[3];
  #pragma unroll
  for (int off = 32; off; off >>= 1) {
    sum += __shfl_xor(sum, off);
    sq  += __shfl_xor(sq, off);
  }
  const float mean = sum * (1.f / 256.f);
  const float var = sq * (1.f / 256.f) - mean * mean;
  const float rs = rsqrtf(var + 1e-5f);
  float4 gg = ((const float4*)g)[lane];
  float4 bb = ((const float4*)beta)[lane];
  float4 ov;
  ov.x = (v[0] - mean) * rs * gg.x + bb.x;
  ov.y = (v[1] - mean) * rs * gg.y + bb.y;
  ov.z = (v[2] - mean) * rs * gg.z + bb.z;
  ov.w = (v[3] - mean) * rs * gg.w + bb.w;
  ((float4*)g_x)[row * 64 + lane] = ov;
  short4v sv;
  sv[0] = (short)f2b(ov.x); sv[1] = (short)f2b(ov.y);
  sv[2] = (short)f2b(ov.z); sv[3] = (short)f2b(ov.w);
  *(short4v*)&g_xb[(row * 64 + lane) * 4] = sv;
  if (do_pos) {
    float4 pv = ((const float4*)g_pos)[row * 64 + lane];
    short4v qv;
    qv[0] = (short)f2b(ov.x + pv.x); qv[1] = (short)f2b(ov.y + pv.y);
    qv[2] = (short)f2b(ov.z + pv.z); qv[3] = (short)f2b(ov.w + pv.w);
    *(short4v*)&g_qkb[(row * 64 + lane) * 4] = qv;
  }
}

// ---------------------------------------------------------------------------
extern "C" void kernel_launch(void* const* d_in, const int* in_sizes, int n_in,
                              void* d_out, int out_size, void* d_ws, size_t ws_size,
                              hipStream_t stream) {
  const float* src  = (const float*)d_in[0];
  const float* pose = (const float*)d_in[1];
  const float* Wq   = (const float*)d_in[2];
  const float* Wk   = (const float*)d_in[3];
  const float* Wv   = (const float*)d_in[4];
  const float* Wo   = (const float*)d_in[5];
  const float* bo   = (const float*)d_in[6];
  const float* cw   = (const float*)d_in[7];
  const float* cb   = (const float*)d_in[8];
  const float* nk   = (const float*)d_in[9];
  const float* nv   = (const float*)d_in[10];
  const float* ln1g = (const float*)d_in[11];
  const float* ln1b = (const float*)d_in[12];
  const float* ln2g = (const float*)d_in[13];
  const float* ln2b = (const float*)d_in[14];
  const float* W1   = (const float*)d_in[15];
  const float* b1   = (const float*)d_in[16];
  const float* W2   = (const float*)d_in[17];
  const float* b2   = (const float*)d_in[18];

  const int MT = Bsz * Tt;        // 16000
  const dim3 tgrid(Tt / 32, Dm / 32, Bsz);

  // g_wb layout: per-layer [Wk|Wq] at l*131072; then Wv, Wo, W1, W2.
  const int OV = 262144, OO = 393216, O1 = 524288, O2 = 1572864;
  wconv_all_k<<<10240, 256, 0, stream>>>(Wk, Wq, Wv, Wo, W1, W2);
  trans_in2_k<<<tgrid, 256, 0, stream>>>(src, pose);  // x, xb, pos, qkb

  const int MB = MT / 128;  // 125 m-blocks
  for (int l = 0; l < 2; ++l) {
    const float* bo_l = bo + (size_t)l * Dm;
    const float* cw_l = cw + (size_t)l * Dm * 64;
    const float* cb_l = cb + (size_t)l * Dm;
    const float* nk_l = nk + (size_t)l * Bsz * Dm;
    const float* nv_l = nv + (size_t)l * Bsz * Dm;
    const float* b1_l = b1 + (size_t)l * FFd;
    const float* b2_l = b2 + (size_t)l * Dm;
    const int wkq = l * 131072;
    const int wv = OV + l * 65536, wo = OO + l * 65536;
    const int w1 = O1 + l * 524288, w2 = O2 + l * 524288;

    // [k|q] = qkb @ [Wk|Wq]^T : k -> tb, q -> qb (N=512 dual-dest, NB=8)
    gemm2_k<64, true, false, false, false, true><<<8 * MB, 256, 0, stream>>>(
        1, wkq, nullptr, 2, 4, 8, MT, 512, Dm);
    // v = xb @ Wv^T -> ffh (free until FF1)  (NB=4)
    gemm2_k<64, false, false, false, false, true><<<4 * MB, 256, 0, stream>>>(
        0, wv, nullptr, 3, 3, 4, MT, Dm, Dm);
    // compress K (tb->kc) and V (ffh->vc) in one dispatch
    compress2_k<<<dim3(50, Bsz, 2), 256, 0, stream>>>(cw_l, cb_l, nk_l, nv_l);
    // kvm = (1/16) kc^T vc
    kvout1_k<<<dim3(Bsz * Hh, JCH), 256, 0, stream>>>();
    kvout2_k<<<Bsz * Hh, 256, 0, stream>>>();
    // W' = kvm (×) Wo  (per-b fused attn+Wo weights)
    wo2_k<<<dim3(Dm, Bsz), 256, 0, stream>>>(wo);
    // t = qb @ W'^T + bo (fp32, per-b) ; x = LN(x + t)
    gemm2_k<64, false, true, false, true, false><<<Bsz * 13 * 4, 256, 0, stream>>>(
        4, 0, bo_l, 2, 2, 4, MT, Dm, Dm);
    ln_k<<<MT / 4, 256, 0, stream>>>(2, -1, ln1g + l * Dm, ln1b + l * Dm, 0);

    // FF1: ffh = bf16(relu(xb @ W1^T + b1))  [NB=32, grid 4000]
    gemm2_k<64, false, false, true, true, true><<<32 * MB, 256, 0, stream>>>(
        0, w1, b1_l, 3, 3, 32, MT, FFd, Dm);
    // FF2: qk = ffh @ W2^T + b2 (fp32)  [NB=4, grid 500]
    gemm2_k<64, false, false, false, true, false><<<4 * MB, 256, 0, stream>>>(
        3, w2, b2_l, 1, 1, 4, MT, Dm, FFd);
    // LN2: layer 0 fused with next layer's pos-add (writes qkb).
    ln_k<<<MT / 4, 256, 0, stream>>>(1, -1, ln2g + l * Dm, ln2b + l * Dm,
                                     l == 0 ? 1 : 0);
  }

  trans_out_k<<<tgrid, 256, 0, stream>>>((float*)d_out);
}